// Round 6
// baseline (2954.805 us; speedup 1.0000x reference)
//
#include <hip/hip_runtime.h>

// ============================================================================
// SelectionRNN on MI355X — round 13: 4 independent batch-classes (de-lockstep).
// Round 12 post-mortem: dataflow barrier + slack = NEUTRAL. With VALU 12% /
// MFMA 10% / HBM 8%, the interval is the L0 class's serial chain (drain ->
// stamp -> observe -> 128KB coherent load -> compute) walked in lockstep by
// all WGs. The batch dim is embarrassingly parallel and mt wave-pairs already
// own 16-batch tiles (A-frags, glds rows, hsh rows are mt-local).
// This round: split into 4 independent recurrence classes (one per mt):
//  * stamps per (WG, mt): idx=(bid*4+mt), 8 replicas, 64B lines (bar 512KB).
//  * per-pair sync: 2-wave LDS flag barriers (release/acquire) replace all
//    in-loop __syncthreads. Pair = waves {mt, mt+4} (kw 0/1).
//  * polls per class: L0 pair: L0(g',mt) >= s+1 (thread p polls g'=p) and
//    L1(g',mt) >= s-1 (p<64, pre1 WAR, 4-slot). L1 pair: L0 >= s+1 (pre1
//    data, drained before L0 stamp s+1), L1 >= s+1.
//  * gate/publish threads remapped pair-local: p=(kw<<6)|lane, b=16mt+(p>>3).
//  * initial stagger mt*~1.1us to seed class pipelining.
// Compute, layouts, pre1 flow, publish formats identical to round 12.
// ============================================================================

typedef __bf16 bf16x8 __attribute__((ext_vector_type(8)));
typedef float f32x4 __attribute__((ext_vector_type(4)));
typedef int i32x4 __attribute__((ext_vector_type(4)));

__device__ __forceinline__ unsigned short f2bf(float f) {
  unsigned u = __float_as_uint(f);
  u = u + 0x7FFFu + ((u >> 16) & 1u);   // RNE (inputs finite)
  return (unsigned short)(u >> 16);
}
__device__ __forceinline__ float sigm_(float x) { return 1.f / (1.f + __expf(-x)); }
__device__ __forceinline__ float tanh_(float x) { return 1.f - 2.f / (__expf(2.f * x) + 1.f); }

// fragment-order element offset for h value of (batch b, unit u):
__device__ __forceinline__ int hxoff(int b, int u) {
  return (b >> 4) * 16384 + (u >> 5) * 512 + ((u >> 3) & 3) * 128 + (b & 15) * 8 + (u & 7);
}

// ---------------------------------------------------------------------------
__global__ void cvt_kernel(const float* __restrict__ s, unsigned short* __restrict__ d, int n) {
  int i = (blockIdx.x * 256 + threadIdx.x) * 4;
  if (i < n) {
    float4 v = *reinterpret_cast<const float4*>(s + i);
    ushort4 o = make_ushort4(f2bf(v.x), f2bf(v.y), f2bf(v.z), f2bf(v.w));
    *reinterpret_cast<ushort4*>(d + i) = o;
  }
}

// ---------------------------------------------------------------------------
// prep: weighted hidden, state init, hX init (fragment order), bias prep,
// barrier clear (512KB across all 128 blocks). grid 128 x 256.
// h0 initial -> parity 0; h1 initial -> parity 1 (lag pipeline).
// ---------------------------------------------------------------------------
__global__ __launch_bounds__(256) void prep_kernel(
    const float* __restrict__ clstm, const float* __restrict__ hidden,
    const float* __restrict__ cell, const int* __restrict__ lens,
    float* __restrict__ hstate, float* __restrict__ cstate,
    unsigned short* __restrict__ h0buf, unsigned short* __restrict__ h1buf,
    const float* __restrict__ bih0, const float* __restrict__ bhh0,
    const float* __restrict__ bih1, const float* __restrict__ bhh1,
    float* __restrict__ bias0, float* __restrict__ bias1p,
    unsigned* __restrict__ bar) {
  const int tid = threadIdx.x, blk = blockIdx.x;
  const int l = blk >> 6, b = blk & 63;
  const float* crow = clstm + b * 1024;
  const float* hrow = hidden + ((size_t)l * 64 + b) * 1024;
  float cmn = 3.4e38f, cmx = -3.4e38f, hmn = 3.4e38f, hmx = -3.4e38f;
  for (int i = tid; i < 1024; i += 256) {
    float c = crow[i], h = hrow[i];
    cmn = fminf(cmn, c); cmx = fmaxf(cmx, c);
    hmn = fminf(hmn, h); hmx = fmaxf(hmx, h);
  }
#pragma unroll
  for (int off = 32; off > 0; off >>= 1) {
    cmn = fminf(cmn, __shfl_xor(cmn, off));
    cmx = fmaxf(cmx, __shfl_xor(cmx, off));
    hmn = fminf(hmn, __shfl_xor(hmn, off));
    hmx = fmaxf(hmx, __shfl_xor(hmx, off));
  }
  __shared__ float red[4][4];
  int wv = tid >> 6;
  if ((tid & 63) == 0) { red[wv][0] = cmn; red[wv][1] = cmx; red[wv][2] = hmn; red[wv][3] = hmx; }
  __syncthreads();
  cmn = fminf(fminf(red[0][0], red[1][0]), fminf(red[2][0], red[3][0]));
  cmx = fmaxf(fmaxf(red[0][1], red[1][1]), fmaxf(red[2][1], red[3][1]));
  hmn = fminf(fminf(red[0][2], red[1][2]), fminf(red[2][2], red[3][2]));
  hmx = fmaxf(fmaxf(red[0][3], red[1][3]), fmaxf(red[2][3], red[3][3]));
  const float crange = cmx - cmn, hrange = hmx - hmn;
  const int len = lens[b];
  const size_t base = ((size_t)l * 64 + b) * 1024;
  unsigned short* dst = (l == 0) ? h0buf : (h1buf + 65536);  // h1 -> parity 1
  for (int i = tid; i < 1024; i += 256) {
    float cv = crow[i], hv = hrow[i];
    float s = (crange > 0.f) ? (cv - cmn) / crange : cv;
    float s2 = (hrange > 0.f) ? (hmn + s * hrange) : s;
    float cc = (len == 0) ? cv : s2;
    float w = 0.5f * hv + 0.5f * cc;          // HIDDEN_WEIGHT = 0.5
    hstate[base + i] = w;
    cstate[base + i] = cell[base + i];
    dst[hxoff(b, i)] = f2bf(w);
  }
  for (int n = tid; n < 1024; n += 256) bar[blk * 1024 + n] = 0u;  // 512KB total
  if (blk == 0) {
    for (int n = tid; n < 4096; n += 256) {
      bias0[n] = bih0[n] + bhh0[n];
      bias1p[(n & 1023) * 4 + (n >> 10)] = bih1[n] + bhh1[n];
    }
  }
}

// ---------------------------------------------------------------------------
// bf16 MFMA GEMM, 128x128 tile. EPI 0 scatters into rec G2 layout.
// ---------------------------------------------------------------------------
template <int AMODE, int EPI>
__global__ __launch_bounds__(256) void gemm_kernel(
    const void* __restrict__ Ap, const unsigned short* __restrict__ Bw,
    void* __restrict__ Cout, const float* __restrict__ bias,
    const int* __restrict__ lens, int M, int N, int K, int t0) {
  __shared__ unsigned short Al[128][40];
  __shared__ unsigned short Bl[128][40];
  const int tid = threadIdx.x;
  const int m0 = blockIdx.y * 128, n0 = blockIdx.x * 128;
  const int srow = tid >> 2;
  const int c8 = (tid & 3) * 8;
  size_t aoff0, aoff1;
  {
    int r = m0 + srow, r2 = r + 64;
    if (AMODE == 0) {
      aoff0 = (size_t)r * K; aoff1 = (size_t)r2 * K;
    } else {
      aoff0 = ((size_t)(r & 63) * 256 + t0 + (r >> 6)) * K;
      aoff1 = ((size_t)(r2 & 63) * 256 + t0 + (r2 >> 6)) * K;
    }
  }
  const size_t boff0 = (size_t)(n0 + srow) * K, boff1 = (size_t)(n0 + srow + 64) * K;
  const int wave = tid >> 6, lane = tid & 63, ln = lane & 15, quad = lane >> 4;
  const int mq = (wave >> 1) * 64, nq = (wave & 1) * 64;
  f32x4 acc[4][4] = {};
  const int nkt = K >> 5;
  for (int kt = 0; kt < nkt; ++kt) {
    const int kc = kt * 32 + c8;
    if (AMODE == 1) {
      const float* A = (const float*)Ap;
      const float* p0 = A + aoff0 + kc;
      const float* p1 = A + aoff1 + kc;
      float4 v0 = *reinterpret_cast<const float4*>(p0);
      float4 v0b = *reinterpret_cast<const float4*>(p0 + 4);
      float4 v1 = *reinterpret_cast<const float4*>(p1);
      float4 v1b = *reinterpret_cast<const float4*>(p1 + 4);
      *reinterpret_cast<ushort4*>(&Al[srow][c8]) =
          make_ushort4(f2bf(v0.x), f2bf(v0.y), f2bf(v0.z), f2bf(v0.w));
      *reinterpret_cast<ushort4*>(&Al[srow][c8 + 4]) =
          make_ushort4(f2bf(v0b.x), f2bf(v0b.y), f2bf(v0b.z), f2bf(v0b.w));
      *reinterpret_cast<ushort4*>(&Al[srow + 64][c8]) =
          make_ushort4(f2bf(v1.x), f2bf(v1.y), f2bf(v1.z), f2bf(v1.w));
      *reinterpret_cast<ushort4*>(&Al[srow + 64][c8 + 4]) =
          make_ushort4(f2bf(v1b.x), f2bf(v1b.y), f2bf(v1b.z), f2bf(v1b.w));
    } else {
      const unsigned short* A = (const unsigned short*)Ap;
      *reinterpret_cast<int4*>(&Al[srow][c8]) = *reinterpret_cast<const int4*>(A + aoff0 + kc);
      *reinterpret_cast<int4*>(&Al[srow + 64][c8]) = *reinterpret_cast<const int4*>(A + aoff1 + kc);
    }
    *reinterpret_cast<int4*>(&Bl[srow][c8]) = *reinterpret_cast<const int4*>(Bw + boff0 + kc);
    *reinterpret_cast<int4*>(&Bl[srow + 64][c8]) = *reinterpret_cast<const int4*>(Bw + boff1 + kc);
    __syncthreads();
    bf16x8 af[4], bfr[4];
#pragma unroll
    for (int i = 0; i < 4; ++i) {
      af[i] = *reinterpret_cast<const bf16x8*>(&Al[mq + i * 16 + ln][quad * 8]);
      bfr[i] = *reinterpret_cast<const bf16x8*>(&Bl[nq + i * 16 + ln][quad * 8]);
    }
#pragma unroll
    for (int i = 0; i < 4; ++i)
#pragma unroll
      for (int j = 0; j < 4; ++j)
        acc[i][j] = __builtin_amdgcn_mfma_f32_16x16x32_bf16(af[i], bfr[j], acc[i][j], 0, 0, 0);
    __syncthreads();
  }
#pragma unroll
  for (int i = 0; i < 4; ++i) {
    int mmb = m0 + mq + i * 16 + quad * 4;
#pragma unroll
    for (int j = 0; j < 4; ++j) {
      int nn = n0 + nq + j * 16 + ln;
      float bv = bias[nn];
#pragma unroll
      for (int r = 0; r < 4; ++r) {
        int mm = mmb + r;
        float v = acc[i][j][r] + bv;
        if (EPI >= 1) v = fmaxf(v, 0.f);
        if (EPI == 2) {
          if (lens[mm >> 8] == 0) v = 0.f;
          ((float*)Cout)[(size_t)mm * N + nn] = v;
        } else if (EPI == 1) {
          ((unsigned short*)Cout)[(size_t)mm * N + nn] = f2bf(v);
        } else {
          size_t idx = ((size_t)mm * 128 + ((nn >> 3) & 127)) * 32 + (nn & 7) * 4 + (nn >> 10);
          ((float*)Cout)[idx] = v;
        }
      }
    }
  }
}

// ---------------------------------------------------------------------------
// Fused two-layer recurrent kernel. Grid MUST be 192 WGs x 512 threads.
// Pair (mt) = waves {mt, mt+4}; owns batches 16mt..16mt+15, fully decoupled
// class. Per-pair sync via LDS flags; per-class stamps/polls via bar.
// ---------------------------------------------------------------------------
#define HLo(dst, ptr, off) \
  asm volatile("global_load_dwordx4 %0, %1, off offset:" off " sc0 sc1" \
               : "=v"(dst) : "v"(ptr) : "memory")
#define HL4(h0, h1, h2, h3, ptr) \
  HLo(h0, ptr, "0"); HLo(h1, ptr, "1024"); HLo(h2, ptr, "2048"); HLo(h3, ptr, "3072")
#define HLF(dst, ptr) \
  asm volatile("global_load_dwordx4 %0, %1, off sc0 sc1" : "=v"(dst) : "v"(ptr) : "memory")
#define HST(ptr, val) \
  asm volatile("global_store_dwordx4 %0, %1, off sc0 sc1" :: "v"(ptr), "v"(val) : "memory")

// 2-wave pair barrier via LDS flags (lane0 release-store, all lanes acquire-poll)
#define PSYNC(ph, ep) do { \
    if (lane == 0) \
      __hip_atomic_store(&flg[mt][kw][ph], (unsigned)(ep), __ATOMIC_RELEASE, \
                         __HIP_MEMORY_SCOPE_WORKGROUP); \
    while (__hip_atomic_load(&flg[mt][kw ^ 1][ph], __ATOMIC_ACQUIRE, \
                             __HIP_MEMORY_SCOPE_WORKGROUP) < (unsigned)(ep)) \
      __builtin_amdgcn_s_sleep(1); \
  } while (0)

__global__ __launch_bounds__(512) void rec2_kernel(
    const unsigned short* __restrict__ whh0b,
    const unsigned short* __restrict__ wih1b,
    const unsigned short* __restrict__ whh1b,
    const float* __restrict__ G2,             // [64*64][128][32] L0 preacts
    const float* __restrict__ bias1p,         // [1024][4]
    unsigned short* __restrict__ h0buf,       // [2][65536] bf16, fragment order
    unsigned short* __restrict__ h1buf,       // [2][65536] bf16, fragment order
    float* __restrict__ pre1buf,              // [4][64][1024][4] f32 (4 slots)
    float* __restrict__ hstate, float* __restrict__ cstate,
    unsigned short* __restrict__ h1out,       // [64][256][1024] bf16
    const int* __restrict__ lens, int t0, int nint, unsigned* __restrict__ bar) {
  __shared__ unsigned short wlds[32 * 1032];  // B cols 32..63 (shared, RO)
  __shared__ float glds[2][64][73];           // rows partitioned by mt
  __shared__ unsigned short hsh[64][16];      // rows partitioned by mt
  __shared__ unsigned flg[4][2][4];           // [mt][kw][phase]
  const int tid = threadIdx.x;
  const int bid = blockIdx.x;
  const bool isL1 = bid >= 128;
  const int g = bid & 127;                    // L0: 0..127; L1: 0..63
  if (tid < 32) ((unsigned*)flg)[tid] = 0;
  // ---- stage LDS weight cols 32..63 (32 rows; 16 thr/row, 64 shorts ea) ----
  {
    int r = tid >> 4;                         // 0..31
    int c0 = (tid & 15) * 64;
    const unsigned short* src;
    if (!isL1)                                // cols 32..63: Wih1 gates 0..3
      src = wih1b + (size_t)((r >> 3) * 1024 + g * 8 + (r & 7)) * 1024;
    else                                      // cols 32..63: Whh1 gates g,o
      src = whh1b + (size_t)((2 + (r >> 4)) * 1024 + g * 16 + (r & 15)) * 1024;
    const i32x4* s4 = reinterpret_cast<const i32x4*>(src + c0);
    i32x4* dst = reinterpret_cast<i32x4*>(wlds + r * 1032 + c0);
#pragma unroll
    for (int j = 0; j < 8; ++j) dst[j] = s4[j];
  }
  const int wave = tid >> 6, lane = tid & 63, ln = lane & 15, quad = lane >> 4;
  const int mt = wave & 3, kw = wave >> 2;
  const int p = (kw << 6) | lane;             // pair-local 0..127
  // ---- B cols 0..15 (bregA) and 16..31 (bregB) in registers ----
  bf16x8 bregA[16], bregB[16];
  {
    const unsigned short *bpA, *bpB;
    if (!isL1) {
      bpA = whh0b + (size_t)((ln >> 3) * 1024 + g * 8 + (ln & 7)) * 1024 + kw * 512 + quad * 8;
      bpB = whh0b + (size_t)((2 + (ln >> 3)) * 1024 + g * 8 + (ln & 7)) * 1024 + kw * 512 + quad * 8;
    } else {
      bpA = whh1b + (size_t)(g * 16 + ln) * 1024 + kw * 512 + quad * 8;
      bpB = whh1b + (size_t)(1024 + g * 16 + ln) * 1024 + kw * 512 + quad * 8;
    }
#pragma unroll
    for (int kt = 0; kt < 16; ++kt) {
      bregA[kt] = *reinterpret_cast<const bf16x8*>(bpA + kt * 32);
      bregB[kt] = *reinterpret_cast<const bf16x8*>(bpB + kt * 32);
    }
  }
  // ---- per-thread owner state (pair-local batch) ----
  const int b = mt * 16 + (p >> 3), ul = p & 7;
  const size_t sb0 = (size_t)(isL1 ? 65536 : 0) + (size_t)b * 1024 +
                     (isL1 ? g * 16 + ul : g * 8 + ul);
  float cm0 = cstate[sb0], hm0 = hstate[sb0];
  float cm1 = 0.f, hm1 = 0.f;
  if (isL1) { cm1 = cstate[sb0 + 8]; hm1 = hstate[sb0 + 8]; }
  int lv0 = lens[b];
  const int len = lv0 < 1 ? 1 : lv0;
  int lvA = lens[mt * 16 + ln];
  const int lenmA = lvA < 1 ? 1 : lvA;        // A-lane batch clamp (pre1 mask)
  f32x4 b1a = {0.f, 0.f, 0.f, 0.f}, b1b = {0.f, 0.f, 0.f, 0.f};
  if (isL1) {
    b1a = *reinterpret_cast<const f32x4*>(bias1p + (g * 16 + ul) * 4);
    b1b = *reinterpret_cast<const f32x4*>(bias1p + (g * 16 + 8 + ul) * 4);
  }
  int lenp = 257;
  if (isL1 && p < 32) { int lv = lens[mt * 16 + (p >> 1)]; lenp = lv < 1 ? 1 : lv; }
  // publish offsets (valid for publishing p only)
  const int puboff = mt * 16384 + (g >> 2) * 512 + (g & 3) * 128 + (p & 15) * 8;
  const int pub1off = mt * 16384 + (g >> 1) * 512 + ((g * 2 + (p & 1)) & 3) * 128 +
                      ((p >> 1) & 15) * 8;
  const bf16x8 z8 = {};
  const i32x4 zi = {};
  __syncthreads();   // wlds + flags ready (only WG-wide sync in the kernel)

  for (int k = 0; k < nint; ++k) {
    const int s = t0 + k;
    if (k == 0 && mt) {                        // seed class stagger ~mt*1.1us
      for (int i = 0; i < mt * 6; ++i) __builtin_amdgcn_s_sleep(7);
    }
    const bool actG = (!isL1) && (k < 64);            // L0 gates for step s
    const bool actP = (!isL1) && (s >= 1) && (s <= 256); // L0 pre1(s-1)
    const bool actL = isL1 && (s >= 2);               // L1 step s-2
    if (actG || actP || actL) {
      // ---- pre1 loads first (L1), then h fragment loads ----
      f32x4 pga = {0.f, 0.f, 0.f, 0.f}, pgb = {0.f, 0.f, 0.f, 0.f};
      if (isL1) {
        const float* pr = pre1buf + (size_t)((s - 2) & 3) * 262144 +
                          ((size_t)b * 1024 + g * 16) * 4;
        HLF(pga, pr + ul * 4);
        HLF(pgb, pr + (8 + ul) * 4);
      }
      bf16x8 hf[16];
      const unsigned short* pp = (isL1 ? h1buf + ((s - 1) & 1) * 65536
                                       : h0buf + (s & 1) * 65536) +
                                 mt * 16384 + kw * 8192 + lane * 8;
      HL4(hf[0], hf[1], hf[2], hf[3], pp);
      HL4(hf[4], hf[5], hf[6], hf[7], pp + 2048);
      HL4(hf[8], hf[9], hf[10], hf[11], pp + 4096);
      HL4(hf[12], hf[13], hf[14], hf[15], pp + 6144);
      if (actG)
        pga = *reinterpret_cast<const f32x4*>(
            G2 + (((size_t)(k * 64 + b)) * 128 + g) * 32 + ul * 4);
      // ---- MFMA: kt 0..7 overlap tail of h-load ----
      const bool maskA = (!isL1) && ((s - 1) >= lenmA);  // zero h0 for padded
      f32x4 acc0 = {0.f, 0.f, 0.f, 0.f}, acc1 = acc0, acc2 = acc0, acc3 = acc0;
      const unsigned short* wp = wlds + ln * 1032 + kw * 512 + quad * 8;
      asm volatile("s_waitcnt vmcnt(8)" ::: "memory");
      __builtin_amdgcn_sched_barrier(0);
#pragma unroll
      for (int kt = 0; kt < 8; ++kt) {
        const unsigned short* c = wp + kt * 32;
        bf16x8 bC = *reinterpret_cast<const bf16x8*>(c);           // cols 32..47
        bf16x8 bD = *reinterpret_cast<const bf16x8*>(c + 16512);   // cols 48..63
        bf16x8 a_ = hf[kt];
        acc0 = __builtin_amdgcn_mfma_f32_16x16x32_bf16(a_, bregA[kt], acc0, 0, 0, 0);
        acc1 = __builtin_amdgcn_mfma_f32_16x16x32_bf16(a_, bregB[kt], acc1, 0, 0, 0);
        bf16x8 am = maskA ? z8 : a_;   // L0: mask Wih1 input on padded batches
        acc2 = __builtin_amdgcn_mfma_f32_16x16x32_bf16(am, bC, acc2, 0, 0, 0);
        acc3 = __builtin_amdgcn_mfma_f32_16x16x32_bf16(am, bD, acc3, 0, 0, 0);
      }
      asm volatile("s_waitcnt vmcnt(0)" ::: "memory");
      __builtin_amdgcn_sched_barrier(0);
#pragma unroll
      for (int kt = 8; kt < 16; ++kt) {
        const unsigned short* c = wp + kt * 32;
        bf16x8 bC = *reinterpret_cast<const bf16x8*>(c);
        bf16x8 bD = *reinterpret_cast<const bf16x8*>(c + 16512);
        bf16x8 a_ = hf[kt];
        acc0 = __builtin_amdgcn_mfma_f32_16x16x32_bf16(a_, bregA[kt], acc0, 0, 0, 0);
        acc1 = __builtin_amdgcn_mfma_f32_16x16x32_bf16(a_, bregB[kt], acc1, 0, 0, 0);
        bf16x8 am = maskA ? z8 : a_;
        acc2 = __builtin_amdgcn_mfma_f32_16x16x32_bf16(am, bC, acc2, 0, 0, 0);
        acc3 = __builtin_amdgcn_mfma_f32_16x16x32_bf16(am, bD, acc3, 0, 0, 0);
      }
      // ---- kw reduce through LDS (pair-local rows) ----
#pragma unroll
      for (int r = 0; r < 4; ++r) {
        float* gp = &glds[kw][mt * 16 + quad * 4 + r][0];
        gp[ln] = acc0[r]; gp[16 + ln] = acc1[r];
        gp[32 + ln] = acc2[r]; gp[48 + ln] = acc3[r];
      }
      PSYNC(0, k + 1);   // A: pair's glds complete
      const float* g0 = &glds[0][b][0];
      const float* g1 = &glds[1][b][0];
      if (actG) {        // L0 gates (cols: gate*8+ul)
        float pi = g0[ul] + g1[ul] + pga.x;
        float pf = g0[8 + ul] + g1[8 + ul] + pga.y;
        float pgg = g0[16 + ul] + g1[16 + ul] + pga.z;
        float po = g0[24 + ul] + g1[24 + ul] + pga.w;
        float ig = sigm_(pi), fg = sigm_(pf), gv = tanh_(pgg), og = sigm_(po);
        float cn_ = fg * cm0 + ig * gv;
        float hn_ = og * tanh_(cn_);
        if (s < len) { cm0 = cn_; hm0 = hn_; }
        hsh[b][ul] = f2bf(hm0);
      }
      if (actP) {        // L0 pre1(s-1) = Wih1 @ h0_masked, f32 float4
        f32x4 pv;
        pv.x = g0[32 + ul] + g1[32 + ul];
        pv.y = g0[40 + ul] + g1[40 + ul];
        pv.z = g0[48 + ul] + g1[48 + ul];
        pv.w = g0[56 + ul] + g1[56 + ul];
        float* pd = pre1buf + (size_t)((s - 1) & 3) * 262144 +
                    (size_t)b * 4096 + g * 32 + ul * 4;
        HST(pd, pv);
      }
      if (actL) {        // L1 gates, 2 units/thread (cols: gate*16+iu)
        {
          float pi = g0[ul] + g1[ul] + pga.x + b1a.x;
          float pf = g0[16 + ul] + g1[16 + ul] + pga.y + b1a.y;
          float pgg = g0[32 + ul] + g1[32 + ul] + pga.z + b1a.z;
          float po = g0[48 + ul] + g1[48 + ul] + pga.w + b1a.w;
          float ig = sigm_(pi), fg = sigm_(pf), gv = tanh_(pgg), og = sigm_(po);
          float cn_ = fg * cm0 + ig * gv;
          float hn_ = og * tanh_(cn_);
          if (s - 2 < len) { cm0 = cn_; hm0 = hn_; }
          hsh[b][ul] = f2bf(hm0);
        }
        {
          int iu = 8 + ul;
          float pi = g0[iu] + g1[iu] + pgb.x + b1b.x;
          float pf = g0[16 + iu] + g1[16 + iu] + pgb.y + b1b.y;
          float pgg = g0[32 + iu] + g1[32 + iu] + pgb.z + b1b.z;
          float po = g0[48 + iu] + g1[48 + iu] + pgb.w + b1b.w;
          float ig = sigm_(pi), fg = sigm_(pf), gv = tanh_(pgg), og = sigm_(po);
          float cn_ = fg * cm1 + ig * gv;
          float hn_ = og * tanh_(cn_);
          if (s - 2 < len) { cm1 = cn_; hm1 = hn_; }
          hsh[b][iu] = f2bf(hm1);
        }
      }
      // kw1 wave: drain pre1 before signaling (stamper relies on it)
      if (kw) { asm volatile("s_waitcnt vmcnt(0)" ::: "memory"); }
      PSYNC(1, k + 1);   // B: gates done, hsh ready, kw1 stores drained
      // ---- publish h (pair's 16 batches) + drains ----
      if (!isL1) {
        if (actG && p < 16) {
          i32x4 v = *reinterpret_cast<const i32x4*>(&hsh[mt * 16 + p][0]);
          unsigned short* d = h0buf + ((s + 1) & 1) * 65536 + puboff;
          HST(d, v);
        }
        asm volatile("s_waitcnt vmcnt(0)" ::: "memory");  // pre1 + publish
      } else {
        if (p < 32) {
          const int pb = mt * 16 + (p >> 1), half = p & 1;
          i32x4 v = *reinterpret_cast<const i32x4*>(&hsh[pb][half * 8]);
          unsigned short* d = h1buf + (s & 1) * 65536 + pub1off;
          HST(d, v);
          const int t = s - 2;
          i32x4 vo = (t < lenp) ? v : zi;
          *reinterpret_cast<i32x4*>(h1out + ((size_t)pb * 256 + t) * 1024 +
                                    g * 16 + half * 8) = vo;
        }
        asm volatile("s_waitcnt vmcnt(1)" ::: "memory");  // h1buf retired
      }
    }
    // ---- class stamp (fire-and-forget) + dependency-exact class polls ----
    if (p == 0) {
      const unsigned val = (unsigned)(s + 1);
      const int sidx = (bid * 4 + mt) * 8;
#pragma unroll
      for (int rep = 0; rep < 8; ++rep)
        __hip_atomic_store(bar + ((sidx + rep) << 4), val,
                           __ATOMIC_RELAXED, __HIP_MEMORY_SCOPE_AGENT);
    }
    const bool lastk = (k == nint - 1) && (nint == 66);  // final chunk tail
    if (!lastk) {
      {  // class L0 stamps >= s+1 (both layers need this)
        const unsigned* lp = bar + (((p * 4 + mt) * 8 + (bid & 7)) << 4);
        while ((int)__hip_atomic_load(lp, __ATOMIC_RELAXED,
                                      __HIP_MEMORY_SCOPE_AGENT) < s + 1)
          __builtin_amdgcn_s_sleep(2);
      }
      if (p < 64) {  // class L1 stamps: L0 needs >= s-1 (pre1 WAR); L1 >= s+1
        const int tgt = isL1 ? (s + 1) : (s - 1);
        if (tgt > 0) {
          const unsigned* lp = bar + ((((128 + p) * 4 + mt) * 8 + (bid & 7)) << 4);
          while ((int)__hip_atomic_load(lp, __ATOMIC_RELAXED,
                                        __HIP_MEMORY_SCOPE_AGENT) < tgt)
            __builtin_amdgcn_s_sleep(2);
        }
      }
      PSYNC(2, k + 1);   // C: both waves observed their poll shares
    }
  }
  hstate[sb0] = hm0; cstate[sb0] = cm0;
  if (isL1) { hstate[sb0 + 8] = hm1; cstate[sb0 + 8] = cm1; }
}

// ---------------------------------------------------------------------------
__global__ void final_kernel(const float* __restrict__ hstate, const float* __restrict__ cstate,
                             const int* __restrict__ lens, float* __restrict__ out) {
  int i = blockIdx.x * 256 + threadIdx.x;   // [L][B][H]
  int b = (i >> 10) & 63;
  float z = (lens[b] == 0) ? 0.f : 1.f;
  out[4194304 + i] = z * hstate[i];
  out[4325376 + i] = z * cstate[i];
}

// ---------------------------------------------------------------------------
extern "C" void kernel_launch(void* const* d_in, const int* in_sizes, int n_in,
                              void* d_out, int out_size, void* d_ws, size_t ws_size,
                              hipStream_t stream) {
  const float* x = (const float*)d_in[0];
  const float* clstm = (const float*)d_in[1];
  const float* hidden = (const float*)d_in[2];
  const float* cell = (const float*)d_in[3];
  const int* lens = (const int*)d_in[4];
  const float* wih0 = (const float*)d_in[5];
  const float* whh0 = (const float*)d_in[6];
  const float* bih0 = (const float*)d_in[7];
  const float* bhh0 = (const float*)d_in[8];
  const float* wih1 = (const float*)d_in[9];
  const float* whh1 = (const float*)d_in[10];
  const float* bih1 = (const float*)d_in[11];
  const float* bhh1 = (const float*)d_in[12];
  const float* w1 = (const float*)d_in[13];
  const float* b1 = (const float*)d_in[14];
  const float* w2 = (const float*)d_in[15];
  const float* b2 = (const float*)d_in[16];
  float* out = (float*)d_out;

  char* ws = (char*)d_ws;
  size_t off = 0;
  auto alloc = [&](size_t bytes) -> void* {
    void* p = ws + off;
    off += (bytes + 255) & ~(size_t)255;
    return p;
  };
  unsigned short* wih0_b = (unsigned short*)alloc(2097152ull * 2);
  unsigned short* whh0_b = (unsigned short*)alloc(4194304ull * 2);
  unsigned short* wih1_b = (unsigned short*)alloc(4194304ull * 2);
  unsigned short* whh1_b = (unsigned short*)alloc(4194304ull * 2);
  unsigned short* w1_b = (unsigned short*)alloc(1048576ull * 2);
  unsigned short* w2_b = (unsigned short*)alloc(262144ull * 2);
  float* bias0 = (float*)alloc(4096 * 4);
  float* bias1p = (float*)alloc(4096 * 4);
  float* hstate = (float*)alloc(131072ull * 4);
  float* cstate = (float*)alloc(131072ull * 4);
  unsigned short* h0buf = (unsigned short*)alloc(131072ull * 2);  // 2 parity x 65536
  unsigned short* h1buf = (unsigned short*)alloc(131072ull * 2);
  float* pre1buf = (float*)alloc(1048576ull * 4);                 // 4 slots x 1 MB
  unsigned* bar = (unsigned*)alloc(524288);                       // 512 KB stamps
  float* G = (float*)alloc(16777216ull * 4);          // G2 preacts / mlp hidden
  unsigned short* h1out = (unsigned short*)alloc(16777216ull * 2);

  cvt_kernel<<<2048, 256, 0, stream>>>(wih0, wih0_b, 2097152);
  cvt_kernel<<<4096, 256, 0, stream>>>(whh0, whh0_b, 4194304);
  cvt_kernel<<<4096, 256, 0, stream>>>(wih1, wih1_b, 4194304);
  cvt_kernel<<<4096, 256, 0, stream>>>(whh1, whh1_b, 4194304);
  cvt_kernel<<<1024, 256, 0, stream>>>(w1, w1_b, 1048576);
  cvt_kernel<<<256, 256, 0, stream>>>(w2, w2_b, 262144);

  prep_kernel<<<128, 256, 0, stream>>>(clstm, hidden, cell, lens, hstate, cstate,
                                       h0buf, h1buf, bih0, bhh0, bih1, bhh1,
                                       bias0, bias1p, bar);

  for (int c = 0; c < 4; ++c) {
    gemm_kernel<1, 0><<<dim3(32, 32), 256, 0, stream>>>(x, wih0_b, G, bias0, lens,
                                                        4096, 4096, 512, c * 64);
    rec2_kernel<<<192, 512, 0, stream>>>(whh0_b, wih1_b, whh1_b, G, bias1p,
                                         h0buf, h1buf, pre1buf, hstate, cstate,
                                         h1out, lens, c * 64, (c == 3) ? 66 : 64, bar);
  }
  // MLP head
  gemm_kernel<0, 1><<<dim3(8, 128), 256, 0, stream>>>(h1out, w1_b, (void*)G, b1, lens,
                                                      16384, 1024, 1024, 0);
  gemm_kernel<0, 2><<<dim3(2, 128), 256, 0, stream>>>((const void*)G, w2_b, out, b2, lens,
                                                      16384, 256, 1024, 0);
  final_kernel<<<512, 256, 0, stream>>>(hstate, cstate, lens, out);
}

// Round 7
// 1877.999 us; speedup vs baseline: 1.5734x; 1.5734x over previous
//
#include <hip/hip_runtime.h>

// ============================================================================
// SelectionRNN on MI355X — round 14: revert to round 11 + embed next-chunk
// G2 GEMM into rec2's idle CUs.
// Round 13 post-mortem: 4-class de-lockstep REGRESSED 408->546us (4x sync
// traffic, shared CUs). Reverted. Interval attacks exhausted (5 tries,
// +4.5/+4.5/+3/0/-34%): the ~6.1us step is a coherent-fabric latency chain.
// This round reclaims serialized non-rec time instead: rec2 uses 192/256
// CUs; WGs 192..255 now compute chunk c+1's G2 GEMM (2 tiles x 8 iters per
// WG, ~80us of work under rec2's 405us) into double-buffered G2a/G2b, then
// exit. The 3 standalone inter-chunk gemm dispatches (+gaps) disappear.
// rec WGs (bid<192) are byte-identical to round 11 (best: 405us, passing).
// LDS 105.5->146KB (still 1 WG/CU). G2 cross-kernel visibility relies on
// dispatch-boundary release/acquire, same as the standalone gemm did.
// ============================================================================

typedef __bf16 bf16x8 __attribute__((ext_vector_type(8)));
typedef float f32x4 __attribute__((ext_vector_type(4)));
typedef int i32x4 __attribute__((ext_vector_type(4)));

__device__ __forceinline__ unsigned short f2bf(float f) {
  unsigned u = __float_as_uint(f);
  u = u + 0x7FFFu + ((u >> 16) & 1u);   // RNE (inputs finite)
  return (unsigned short)(u >> 16);
}
__device__ __forceinline__ float sigm_(float x) { return 1.f / (1.f + __expf(-x)); }
__device__ __forceinline__ float tanh_(float x) { return 1.f - 2.f / (__expf(2.f * x) + 1.f); }

// fragment-order element offset for h value of (batch b, unit u):
__device__ __forceinline__ int hxoff(int b, int u) {
  return (b >> 4) * 16384 + (u >> 5) * 512 + ((u >> 3) & 3) * 128 + (b & 15) * 8 + (u & 7);
}

// ---------------------------------------------------------------------------
__global__ void cvt_kernel(const float* __restrict__ s, unsigned short* __restrict__ d, int n) {
  int i = (blockIdx.x * 256 + threadIdx.x) * 4;
  if (i < n) {
    float4 v = *reinterpret_cast<const float4*>(s + i);
    ushort4 o = make_ushort4(f2bf(v.x), f2bf(v.y), f2bf(v.z), f2bf(v.w));
    *reinterpret_cast<ushort4*>(d + i) = o;
  }
}

// ---------------------------------------------------------------------------
// prep: weighted hidden, state init, hX init (fragment order), bias prep,
// barrier clear. grid 128 (l=blk>>6, b=blk&63) x 256.
// h0 initial -> parity 0; h1 initial -> parity 1 (lag-2 pipeline).
// ---------------------------------------------------------------------------
__global__ __launch_bounds__(256) void prep_kernel(
    const float* __restrict__ clstm, const float* __restrict__ hidden,
    const float* __restrict__ cell, const int* __restrict__ lens,
    float* __restrict__ hstate, float* __restrict__ cstate,
    unsigned short* __restrict__ h0buf, unsigned short* __restrict__ h1buf,
    const float* __restrict__ bih0, const float* __restrict__ bhh0,
    const float* __restrict__ bih1, const float* __restrict__ bhh1,
    float* __restrict__ bias0, float* __restrict__ bias1p,
    unsigned* __restrict__ bar) {
  const int tid = threadIdx.x, blk = blockIdx.x;
  const int l = blk >> 6, b = blk & 63;
  const float* crow = clstm + b * 1024;
  const float* hrow = hidden + ((size_t)l * 64 + b) * 1024;
  float cmn = 3.4e38f, cmx = -3.4e38f, hmn = 3.4e38f, hmx = -3.4e38f;
  for (int i = tid; i < 1024; i += 256) {
    float c = crow[i], h = hrow[i];
    cmn = fminf(cmn, c); cmx = fmaxf(cmx, c);
    hmn = fminf(hmn, h); hmx = fmaxf(hmx, h);
  }
#pragma unroll
  for (int off = 32; off > 0; off >>= 1) {
    cmn = fminf(cmn, __shfl_xor(cmn, off));
    cmx = fmaxf(cmx, __shfl_xor(cmx, off));
    hmn = fminf(hmn, __shfl_xor(hmn, off));
    hmx = fmaxf(hmx, __shfl_xor(hmx, off));
  }
  __shared__ float red[4][4];
  int wv = tid >> 6;
  if ((tid & 63) == 0) { red[wv][0] = cmn; red[wv][1] = cmx; red[wv][2] = hmn; red[wv][3] = hmx; }
  __syncthreads();
  cmn = fminf(fminf(red[0][0], red[1][0]), fminf(red[2][0], red[3][0]));
  cmx = fmaxf(fmaxf(red[0][1], red[1][1]), fmaxf(red[2][1], red[3][1]));
  hmn = fminf(fminf(red[0][2], red[1][2]), fminf(red[2][2], red[3][2]));
  hmx = fmaxf(fmaxf(red[0][3], red[1][3]), fmaxf(red[2][3], red[3][3]));
  const float crange = cmx - cmn, hrange = hmx - hmn;
  const int len = lens[b];
  const size_t base = ((size_t)l * 64 + b) * 1024;
  unsigned short* dst = (l == 0) ? h0buf : (h1buf + 65536);  // h1 -> parity 1
  for (int i = tid; i < 1024; i += 256) {
    float cv = crow[i], hv = hrow[i];
    float s = (crange > 0.f) ? (cv - cmn) / crange : cv;
    float s2 = (hrange > 0.f) ? (hmn + s * hrange) : s;
    float cc = (len == 0) ? cv : s2;
    float w = 0.5f * hv + 0.5f * cc;          // HIDDEN_WEIGHT = 0.5
    hstate[base + i] = w;
    cstate[base + i] = cell[base + i];
    dst[hxoff(b, i)] = f2bf(w);
  }
  if (blk == 0) {
    for (int n = tid; n < 4096; n += 256) {
      bias0[n] = bih0[n] + bhh0[n];
      bias1p[(n & 1023) * 4 + (n >> 10)] = bih1[n] + bhh1[n];
      bar[n] = 0u;
    }
  }
}

// ---------------------------------------------------------------------------
// bf16 MFMA GEMM, 128x128 tile. EPI 0 scatters into rec G2 layout.
// ---------------------------------------------------------------------------
template <int AMODE, int EPI>
__global__ __launch_bounds__(256) void gemm_kernel(
    const void* __restrict__ Ap, const unsigned short* __restrict__ Bw,
    void* __restrict__ Cout, const float* __restrict__ bias,
    const int* __restrict__ lens, int M, int N, int K, int t0) {
  __shared__ unsigned short Al[128][40];
  __shared__ unsigned short Bl[128][40];
  const int tid = threadIdx.x;
  const int m0 = blockIdx.y * 128, n0 = blockIdx.x * 128;
  const int srow = tid >> 2;
  const int c8 = (tid & 3) * 8;
  size_t aoff0, aoff1;
  {
    int r = m0 + srow, r2 = r + 64;
    if (AMODE == 0) {
      aoff0 = (size_t)r * K; aoff1 = (size_t)r2 * K;
    } else {
      aoff0 = ((size_t)(r & 63) * 256 + t0 + (r >> 6)) * K;
      aoff1 = ((size_t)(r2 & 63) * 256 + t0 + (r2 >> 6)) * K;
    }
  }
  const size_t boff0 = (size_t)(n0 + srow) * K, boff1 = (size_t)(n0 + srow + 64) * K;
  const int wave = tid >> 6, lane = tid & 63, ln = lane & 15, quad = lane >> 4;
  const int mq = (wave >> 1) * 64, nq = (wave & 1) * 64;
  f32x4 acc[4][4] = {};
  const int nkt = K >> 5;
  for (int kt = 0; kt < nkt; ++kt) {
    const int kc = kt * 32 + c8;
    if (AMODE == 1) {
      const float* A = (const float*)Ap;
      const float* p0 = A + aoff0 + kc;
      const float* p1 = A + aoff1 + kc;
      float4 v0 = *reinterpret_cast<const float4*>(p0);
      float4 v0b = *reinterpret_cast<const float4*>(p0 + 4);
      float4 v1 = *reinterpret_cast<const float4*>(p1);
      float4 v1b = *reinterpret_cast<const float4*>(p1 + 4);
      *reinterpret_cast<ushort4*>(&Al[srow][c8]) =
          make_ushort4(f2bf(v0.x), f2bf(v0.y), f2bf(v0.z), f2bf(v0.w));
      *reinterpret_cast<ushort4*>(&Al[srow][c8 + 4]) =
          make_ushort4(f2bf(v0b.x), f2bf(v0b.y), f2bf(v0b.z), f2bf(v0b.w));
      *reinterpret_cast<ushort4*>(&Al[srow + 64][c8]) =
          make_ushort4(f2bf(v1.x), f2bf(v1.y), f2bf(v1.z), f2bf(v1.w));
      *reinterpret_cast<ushort4*>(&Al[srow + 64][c8 + 4]) =
          make_ushort4(f2bf(v1b.x), f2bf(v1b.y), f2bf(v1b.z), f2bf(v1b.w));
    } else {
      const unsigned short* A = (const unsigned short*)Ap;
      *reinterpret_cast<int4*>(&Al[srow][c8]) = *reinterpret_cast<const int4*>(A + aoff0 + kc);
      *reinterpret_cast<int4*>(&Al[srow + 64][c8]) = *reinterpret_cast<const int4*>(A + aoff1 + kc);
    }
    *reinterpret_cast<int4*>(&Bl[srow][c8]) = *reinterpret_cast<const int4*>(Bw + boff0 + kc);
    *reinterpret_cast<int4*>(&Bl[srow + 64][c8]) = *reinterpret_cast<const int4*>(Bw + boff1 + kc);
    __syncthreads();
    bf16x8 af[4], bfr[4];
#pragma unroll
    for (int i = 0; i < 4; ++i) {
      af[i] = *reinterpret_cast<const bf16x8*>(&Al[mq + i * 16 + ln][quad * 8]);
      bfr[i] = *reinterpret_cast<const bf16x8*>(&Bl[nq + i * 16 + ln][quad * 8]);
    }
#pragma unroll
    for (int i = 0; i < 4; ++i)
#pragma unroll
      for (int j = 0; j < 4; ++j)
        acc[i][j] = __builtin_amdgcn_mfma_f32_16x16x32_bf16(af[i], bfr[j], acc[i][j], 0, 0, 0);
    __syncthreads();
  }
#pragma unroll
  for (int i = 0; i < 4; ++i) {
    int mmb = m0 + mq + i * 16 + quad * 4;
#pragma unroll
    for (int j = 0; j < 4; ++j) {
      int nn = n0 + nq + j * 16 + ln;
      float bv = bias[nn];
#pragma unroll
      for (int r = 0; r < 4; ++r) {
        int mm = mmb + r;
        float v = acc[i][j][r] + bv;
        if (EPI >= 1) v = fmaxf(v, 0.f);
        if (EPI == 2) {
          if (lens[mm >> 8] == 0) v = 0.f;
          ((float*)Cout)[(size_t)mm * N + nn] = v;
        } else if (EPI == 1) {
          ((unsigned short*)Cout)[(size_t)mm * N + nn] = f2bf(v);
        } else {
          size_t idx = ((size_t)mm * 128 + ((nn >> 3) & 127)) * 32 + (nn & 7) * 4 + (nn >> 10);
          ((float*)Cout)[idx] = v;
        }
      }
    }
  }
}

// ---------------------------------------------------------------------------
// Fused two-layer recurrent kernel + embedded next-chunk G2 GEMM.
// Grid MUST be 256 WGs x 512 threads.
// WGs 0..127  (L0): units 8g..8g+7. cols 0..15 = Whh0 gates i,f (bregA);
//   cols 16..31 = Whh0 gates g,o (bregB); cols 32..63 = Wih1 (wlds).
// WGs 128..191(L1): units 16g..16g+15. cols 0..15 = Whh1 gate i (bregA);
//   16..31 = gate f (bregB); 32..63 = gates g,o (wlds).
// WGs 192..255: chunk-(c+1) G2 GEMM (x @ Wih0^T), 2 tiles/WG x 8 iters,
//   then exit. No interaction with rec WGs.
// wlds: 32 rows x 1032 shorts. glds[2][64][73] reduce.
// Barrier (rec WGs only): 24 groups x 8 arrive; finisher stores s+1 to 8
// replica flags; threads 0..23 poll (replica bid&7); syncthreads fan-out.
// ---------------------------------------------------------------------------
#define HLo(dst, ptr, off) \
  asm volatile("global_load_dwordx4 %0, %1, off offset:" off " sc0 sc1" \
               : "=v"(dst) : "v"(ptr))
#define HL4(h0, h1, h2, h3, ptr) \
  HLo(h0, ptr, "0"); HLo(h1, ptr, "1024"); HLo(h2, ptr, "2048"); HLo(h3, ptr, "3072")
#define HLF(dst, ptr) \
  asm volatile("global_load_dwordx4 %0, %1, off sc0 sc1" : "=v"(dst) : "v"(ptr))
#define HST(ptr, val) \
  asm volatile("global_store_dwordx4 %0, %1, off sc0 sc1" :: "v"(ptr), "v"(val) : "memory")

__global__ __launch_bounds__(512) void rec2_kernel(
    const unsigned short* __restrict__ whh0b,
    const unsigned short* __restrict__ wih1b,
    const unsigned short* __restrict__ whh1b,
    const float* __restrict__ G2,             // [64*64][128][32] L0 preacts
    const float* __restrict__ bias1p,         // [1024][4]
    unsigned short* __restrict__ h0buf,       // [2][65536] bf16, fragment order
    unsigned short* __restrict__ h1buf,       // [2][65536] bf16, fragment order
    float* __restrict__ pre1buf,              // [2][64][1024][4] f32
    float* __restrict__ hstate, float* __restrict__ cstate,
    unsigned short* __restrict__ h1out,       // [64][256][1024] bf16
    const int* __restrict__ lens, int t0, int nint, unsigned* __restrict__ bar,
    const float* __restrict__ xin,            // [64][256][512] f32 input
    const unsigned short* __restrict__ wih0bk,// Wih0 bf16 [4096][512]
    float* __restrict__ Gnext,                // next chunk G2 out
    const float* __restrict__ bias0k,         // [4096]
    int t0n, int do_gemm) {
  __shared__ unsigned short wlds[32 * 1032];  // B cols 32..63
  __shared__ float glds[2][64][73];
  __shared__ unsigned short hsh[64][16];
  __shared__ unsigned short Ag[2][128][40];   // embedded gemm A tiles
  __shared__ unsigned short Bg[2][128][40];   // embedded gemm B tiles
  const int tid = threadIdx.x;
  const int bid = blockIdx.x;

  if (bid >= 192) {     // ---- embedded next-chunk G2 GEMM (2 tiles/WG) ----
    if (!do_gemm) return;
    const int w = bid - 192;                  // 0..63
    const int half = tid >> 8;                // two 256-thread sub-WGs
    const int tl = tid & 255;
    const int srow = tl >> 2;
    const int c8 = (tl & 3) * 8;
    const int wv = tl >> 6, lane2 = tl & 63, ln2 = lane2 & 15, qd = lane2 >> 4;
    const int mq = (wv >> 1) * 64, nq = (wv & 1) * 64;
    for (int it = 0; it < 8; ++it) {
      const int tau = it * 128 + w * 2 + half;          // 0..1023 tile id
      const int m0 = (tau >> 5) * 128, n0 = (tau & 31) * 128;
      size_t aoff0, aoff1;
      {
        int r = m0 + srow, r2 = r + 64;
        aoff0 = ((size_t)(r & 63) * 256 + t0n + (r >> 6)) * 512;
        aoff1 = ((size_t)(r2 & 63) * 256 + t0n + (r2 >> 6)) * 512;
      }
      const size_t boff0 = (size_t)(n0 + srow) * 512;
      const size_t boff1 = (size_t)(n0 + srow + 64) * 512;
      f32x4 acc[4][4] = {};
#pragma unroll 1
      for (int kt = 0; kt < 16; ++kt) {
        const int kc = kt * 32 + c8;
        const float* p0 = xin + aoff0 + kc;
        const float* p1 = xin + aoff1 + kc;
        float4 v0 = *reinterpret_cast<const float4*>(p0);
        float4 v0b = *reinterpret_cast<const float4*>(p0 + 4);
        float4 v1 = *reinterpret_cast<const float4*>(p1);
        float4 v1b = *reinterpret_cast<const float4*>(p1 + 4);
        *reinterpret_cast<ushort4*>(&Ag[half][srow][c8]) =
            make_ushort4(f2bf(v0.x), f2bf(v0.y), f2bf(v0.z), f2bf(v0.w));
        *reinterpret_cast<ushort4*>(&Ag[half][srow][c8 + 4]) =
            make_ushort4(f2bf(v0b.x), f2bf(v0b.y), f2bf(v0b.z), f2bf(v0b.w));
        *reinterpret_cast<ushort4*>(&Ag[half][srow + 64][c8]) =
            make_ushort4(f2bf(v1.x), f2bf(v1.y), f2bf(v1.z), f2bf(v1.w));
        *reinterpret_cast<ushort4*>(&Ag[half][srow + 64][c8 + 4]) =
            make_ushort4(f2bf(v1b.x), f2bf(v1b.y), f2bf(v1b.z), f2bf(v1b.w));
        *reinterpret_cast<int4*>(&Bg[half][srow][c8]) =
            *reinterpret_cast<const int4*>(wih0bk + boff0 + kc);
        *reinterpret_cast<int4*>(&Bg[half][srow + 64][c8]) =
            *reinterpret_cast<const int4*>(wih0bk + boff1 + kc);
        __syncthreads();
        bf16x8 af[4], bfr[4];
#pragma unroll
        for (int i = 0; i < 4; ++i) {
          af[i] = *reinterpret_cast<const bf16x8*>(&Ag[half][mq + i * 16 + ln2][qd * 8]);
          bfr[i] = *reinterpret_cast<const bf16x8*>(&Bg[half][nq + i * 16 + ln2][qd * 8]);
        }
#pragma unroll
        for (int i = 0; i < 4; ++i)
#pragma unroll
          for (int j = 0; j < 4; ++j)
            acc[i][j] = __builtin_amdgcn_mfma_f32_16x16x32_bf16(af[i], bfr[j], acc[i][j], 0, 0, 0);
        __syncthreads();
      }
#pragma unroll
      for (int i = 0; i < 4; ++i) {
        int mmb = m0 + mq + i * 16 + qd * 4;
#pragma unroll
        for (int j = 0; j < 4; ++j) {
          int nn = n0 + nq + j * 16 + ln2;
          float bv = bias0k[nn];
#pragma unroll
          for (int r = 0; r < 4; ++r) {
            int mm = mmb + r;
            float v = acc[i][j][r] + bv;
            size_t idx = ((size_t)mm * 128 + ((nn >> 3) & 127)) * 32 + (nn & 7) * 4 + (nn >> 10);
            Gnext[idx] = v;
          }
        }
      }
    }
    return;
  }

  // ======================= rec path (round 11 verbatim) =====================
  const bool isL1 = bid >= 128;
  const int g = bid & 127;                    // L0: 0..127; L1: 0..63
  // ---- stage LDS weight cols 32..63 (32 rows; 16 thr/row, 64 shorts ea) ----
  {
    int r = tid >> 4;                         // 0..31
    int c0 = (tid & 15) * 64;
    const unsigned short* src;
    if (!isL1)                                // cols 32..63: Wih1 gates 0..3
      src = wih1b + (size_t)((r >> 3) * 1024 + g * 8 + (r & 7)) * 1024;
    else                                      // cols 32..63: Whh1 gates g,o
      src = whh1b + (size_t)((2 + (r >> 4)) * 1024 + g * 16 + (r & 15)) * 1024;
    const i32x4* s4 = reinterpret_cast<const i32x4*>(src + c0);
    i32x4* dst = reinterpret_cast<i32x4*>(wlds + r * 1032 + c0);
#pragma unroll
    for (int j = 0; j < 8; ++j) dst[j] = s4[j];
  }
  const int wave = tid >> 6, lane = tid & 63, ln = lane & 15, quad = lane >> 4;
  const int mt = wave & 3, kw = wave >> 2;
  // ---- B cols 0..15 (bregA) and 16..31 (bregB) in registers ----
  bf16x8 bregA[16], bregB[16];
  {
    const unsigned short *bpA, *bpB;
    if (!isL1) {
      bpA = whh0b + (size_t)((ln >> 3) * 1024 + g * 8 + (ln & 7)) * 1024 + kw * 512 + quad * 8;
      bpB = whh0b + (size_t)((2 + (ln >> 3)) * 1024 + g * 8 + (ln & 7)) * 1024 + kw * 512 + quad * 8;
    } else {
      bpA = whh1b + (size_t)(g * 16 + ln) * 1024 + kw * 512 + quad * 8;
      bpB = whh1b + (size_t)(1024 + g * 16 + ln) * 1024 + kw * 512 + quad * 8;
    }
#pragma unroll
    for (int kt = 0; kt < 16; ++kt) {
      bregA[kt] = *reinterpret_cast<const bf16x8*>(bpA + kt * 32);
      bregB[kt] = *reinterpret_cast<const bf16x8*>(bpB + kt * 32);
    }
  }
  // ---- per-thread owner state ----
  const int b = tid >> 3, ul = tid & 7;
  const size_t sb0 = (size_t)(isL1 ? 65536 : 0) + (size_t)b * 1024 +
                     (isL1 ? g * 16 + ul : g * 8 + ul);
  float cm0 = cstate[sb0], hm0 = hstate[sb0];
  float cm1 = 0.f, hm1 = 0.f;
  if (isL1) { cm1 = cstate[sb0 + 8]; hm1 = hstate[sb0 + 8]; }
  int lv0 = lens[b];
  const int len = lv0 < 1 ? 1 : lv0;
  int lvA = lens[mt * 16 + ln];
  const int lenmA = lvA < 1 ? 1 : lvA;        // A-lane batch clamp (pre1 mask)
  f32x4 b1a = {0.f, 0.f, 0.f, 0.f}, b1b = {0.f, 0.f, 0.f, 0.f};
  if (isL1) {
    b1a = *reinterpret_cast<const f32x4*>(bias1p + (g * 16 + ul) * 4);
    b1b = *reinterpret_cast<const f32x4*>(bias1p + (g * 16 + 8 + ul) * 4);
  }
  int lenp = 257;
  if (isL1 && tid < 128) { int lv = lens[tid >> 1]; lenp = lv < 1 ? 1 : lv; }
  const int puboff = (tid >> 4) * 16384 + (g >> 2) * 512 + (g & 3) * 128 + (tid & 15) * 8;
  const int pub1off = ((tid >> 1) >> 4) * 16384 + (g >> 1) * 512 +
                      ((g * 2 + (tid & 1)) & 3) * 128 + ((tid >> 1) & 15) * 8;
  const bf16x8 z8 = {};
  const i32x4 zi = {};
  __syncthreads();

  for (int k = 0; k < nint; ++k) {
    const int s = t0 + k;
    const bool actG = (!isL1) && (k < 64);            // L0 gates for step s
    const bool actP = (!isL1) && (s >= 1) && (s <= 256); // L0 pre1(s-1)
    const bool actL = isL1 && (s >= 2);               // L1 step s-2
    if (actG || actP || actL) {
      // ---- pre1 loads first (L1), then h fragment loads ----
      f32x4 pga = {0.f, 0.f, 0.f, 0.f}, pgb = {0.f, 0.f, 0.f, 0.f};
      if (isL1) {
        const float* pr = pre1buf + (size_t)(s & 1) * 262144 +
                          ((size_t)b * 1024 + g * 16) * 4;
        HLF(pga, pr + ul * 4);
        HLF(pgb, pr + (8 + ul) * 4);
      }
      bf16x8 hf[16];
      const unsigned short* p = (isL1 ? h1buf + ((s - 1) & 1) * 65536
                                      : h0buf + (s & 1) * 65536) +
                                mt * 16384 + kw * 8192 + lane * 8;
      HL4(hf[0], hf[1], hf[2], hf[3], p);
      HL4(hf[4], hf[5], hf[6], hf[7], p + 2048);
      HL4(hf[8], hf[9], hf[10], hf[11], p + 4096);
      HL4(hf[12], hf[13], hf[14], hf[15], p + 6144);
      if (actG)
        pga = *reinterpret_cast<const f32x4*>(
            G2 + (((size_t)(k * 64 + b)) * 128 + g) * 32 + ul * 4);
      // ---- MFMA: kt 0..7 overlap tail of h-load ----
      const bool maskA = (!isL1) && ((s - 1) >= lenmA);  // zero h0 for padded
      f32x4 acc0 = {0.f, 0.f, 0.f, 0.f}, acc1 = acc0, acc2 = acc0, acc3 = acc0;
      const unsigned short* wp = wlds + ln * 1032 + kw * 512 + quad * 8;
      asm volatile("s_waitcnt vmcnt(8)" ::: "memory");
      __builtin_amdgcn_sched_barrier(0);
#pragma unroll
      for (int kt = 0; kt < 8; ++kt) {
        const unsigned short* c = wp + kt * 32;
        bf16x8 bC = *reinterpret_cast<const bf16x8*>(c);           // cols 32..47
        bf16x8 bD = *reinterpret_cast<const bf16x8*>(c + 16512);   // cols 48..63
        bf16x8 a_ = hf[kt];
        acc0 = __builtin_amdgcn_mfma_f32_16x16x32_bf16(a_, bregA[kt], acc0, 0, 0, 0);
        acc1 = __builtin_amdgcn_mfma_f32_16x16x32_bf16(a_, bregB[kt], acc1, 0, 0, 0);
        bf16x8 am = maskA ? z8 : a_;   // L0: mask Wih1 input on padded batches
        acc2 = __builtin_amdgcn_mfma_f32_16x16x32_bf16(am, bC, acc2, 0, 0, 0);
        acc3 = __builtin_amdgcn_mfma_f32_16x16x32_bf16(am, bD, acc3, 0, 0, 0);
      }
      asm volatile("s_waitcnt vmcnt(0)" ::: "memory");
      __builtin_amdgcn_sched_barrier(0);
#pragma unroll
      for (int kt = 8; kt < 16; ++kt) {
        const unsigned short* c = wp + kt * 32;
        bf16x8 bC = *reinterpret_cast<const bf16x8*>(c);
        bf16x8 bD = *reinterpret_cast<const bf16x8*>(c + 16512);
        bf16x8 a_ = hf[kt];
        acc0 = __builtin_amdgcn_mfma_f32_16x16x32_bf16(a_, bregA[kt], acc0, 0, 0, 0);
        acc1 = __builtin_amdgcn_mfma_f32_16x16x32_bf16(a_, bregB[kt], acc1, 0, 0, 0);
        bf16x8 am = maskA ? z8 : a_;
        acc2 = __builtin_amdgcn_mfma_f32_16x16x32_bf16(am, bC, acc2, 0, 0, 0);
        acc3 = __builtin_amdgcn_mfma_f32_16x16x32_bf16(am, bD, acc3, 0, 0, 0);
      }
      // ---- kw reduce through LDS (single pass, 64 cols) ----
#pragma unroll
      for (int r = 0; r < 4; ++r) {
        float* gp = &glds[kw][mt * 16 + quad * 4 + r][0];
        gp[ln] = acc0[r]; gp[16 + ln] = acc1[r];
        gp[32 + ln] = acc2[r]; gp[48 + ln] = acc3[r];
      }
      __syncthreads();   // A
      const float* g0 = &glds[0][b][0];
      const float* g1 = &glds[1][b][0];
      if (actG) {        // L0 gates (cols: gate*8+ul)
        float pi = g0[ul] + g1[ul] + pga.x;
        float pf = g0[8 + ul] + g1[8 + ul] + pga.y;
        float pgg = g0[16 + ul] + g1[16 + ul] + pga.z;
        float po = g0[24 + ul] + g1[24 + ul] + pga.w;
        float ig = sigm_(pi), fg = sigm_(pf), gv = tanh_(pgg), og = sigm_(po);
        float cn_ = fg * cm0 + ig * gv;
        float hn_ = og * tanh_(cn_);
        if (s < len) { cm0 = cn_; hm0 = hn_; }
        hsh[b][ul] = f2bf(hm0);
      }
      if (actP) {        // L0 pre1(s-1) = Wih1 @ h0_masked(s-1), f32 float4
        f32x4 pv;
        pv.x = g0[32 + ul] + g1[32 + ul];
        pv.y = g0[40 + ul] + g1[40 + ul];
        pv.z = g0[48 + ul] + g1[48 + ul];
        pv.w = g0[56 + ul] + g1[56 + ul];
        float* pd = pre1buf + (size_t)((s - 1) & 1) * 262144 +
                    (size_t)b * 4096 + g * 32 + ul * 4;
        HST(pd, pv);     // drained after publish, before barrier
      }
      if (actL) {        // L1 gates, 2 units/thread (cols: gate*16+iu)
        {
          float pi = g0[ul] + g1[ul] + pga.x + b1a.x;
          float pf = g0[16 + ul] + g1[16 + ul] + pga.y + b1a.y;
          float pgg = g0[32 + ul] + g1[32 + ul] + pga.z + b1a.z;
          float po = g0[48 + ul] + g1[48 + ul] + pga.w + b1a.w;
          float ig = sigm_(pi), fg = sigm_(pf), gv = tanh_(pgg), og = sigm_(po);
          float cn_ = fg * cm0 + ig * gv;
          float hn_ = og * tanh_(cn_);
          if (s - 2 < len) { cm0 = cn_; hm0 = hn_; }
          hsh[b][ul] = f2bf(hm0);
        }
        {
          int iu = 8 + ul;
          float pi = g0[iu] + g1[iu] + pgb.x + b1b.x;
          float pf = g0[16 + iu] + g1[16 + iu] + pgb.y + b1b.y;
          float pgg = g0[32 + iu] + g1[32 + iu] + pgb.z + b1b.z;
          float po = g0[48 + iu] + g1[48 + iu] + pgb.w + b1b.w;
          float ig = sigm_(pi), fg = sigm_(pf), gv = tanh_(pgg), og = sigm_(po);
          float cn_ = fg * cm1 + ig * gv;
          float hn_ = og * tanh_(cn_);
          if (s - 2 < len) { cm1 = cn_; hm1 = hn_; }
          hsh[b][iu] = f2bf(hm1);
        }
      }
      __syncthreads();   // B
      // ---- publish h (fragment order, 16 B/thread) + drains ----
      if (!isL1) {
        if (actG && tid < 64) {
          i32x4 v = *reinterpret_cast<const i32x4*>(&hsh[tid][0]);
          unsigned short* d = h0buf + ((s + 1) & 1) * 65536 + puboff;
          HST(d, v);
        }
        // drains this thread's pre1 store (all 512 thr) and publish (tid<64)
        asm volatile("s_waitcnt vmcnt(0)" ::: "memory");
      } else {
        if (tid < 128) {
          const int pb = tid >> 1, half = tid & 1;
          i32x4 v = *reinterpret_cast<const i32x4*>(&hsh[pb][half * 8]);
          unsigned short* d = h1buf + (s & 1) * 65536 + pub1off;
          HST(d, v);
          const int t = s - 2;
          i32x4 vo = (t < lenp) ? v : zi;
          *reinterpret_cast<i32x4*>(h1out + ((size_t)pb * 256 + t) * 1024 +
                                    g * 16 + half * 8) = vo;
          // vmcnt(1): h1buf HST (older) retired; h1out store may linger
          // (h1out is only read after kernel end).
          asm volatile("s_waitcnt vmcnt(1)" ::: "memory");
        }
      }
    }
    // ---- barrier: 24 groups x 8 arrive; finisher stores s+1 to 8 replica
    //      flags; threads 0..23 poll (replica bid&7); syncthreads fan-out ----
    __syncthreads();
    if (tid == 0) {
      unsigned a = __hip_atomic_fetch_add(bar + ((bid >> 3) << 4), 1u,
                                          __ATOMIC_RELAXED, __HIP_MEMORY_SCOPE_AGENT);
      if ((a & 7u) == 7u) {
        const unsigned val = (unsigned)(s + 1);
        const int gi = bid >> 3;
#pragma unroll
        for (int rep = 0; rep < 8; ++rep)
          __hip_atomic_store(bar + 1024 + ((gi * 8 + rep) << 4), val,
                             __ATOMIC_RELAXED, __HIP_MEMORY_SCOPE_AGENT);
      }
    }
    if (tid < 24) {
      const unsigned tgt = (unsigned)(s + 1);
      while (__hip_atomic_load(bar + 1024 + ((tid * 8 + (bid & 7)) << 4),
                               __ATOMIC_RELAXED, __HIP_MEMORY_SCOPE_AGENT) < tgt)
        __builtin_amdgcn_s_sleep(2);
    }
    __syncthreads();
  }
  hstate[sb0] = hm0; cstate[sb0] = cm0;
  if (isL1) { hstate[sb0 + 8] = hm1; cstate[sb0 + 8] = cm1; }
}

// ---------------------------------------------------------------------------
__global__ void final_kernel(const float* __restrict__ hstate, const float* __restrict__ cstate,
                             const int* __restrict__ lens, float* __restrict__ out) {
  int i = blockIdx.x * 256 + threadIdx.x;   // [L][B][H]
  int b = (i >> 10) & 63;
  float z = (lens[b] == 0) ? 0.f : 1.f;
  out[4194304 + i] = z * hstate[i];
  out[4325376 + i] = z * cstate[i];
}

// ---------------------------------------------------------------------------
extern "C" void kernel_launch(void* const* d_in, const int* in_sizes, int n_in,
                              void* d_out, int out_size, void* d_ws, size_t ws_size,
                              hipStream_t stream) {
  const float* x = (const float*)d_in[0];
  const float* clstm = (const float*)d_in[1];
  const float* hidden = (const float*)d_in[2];
  const float* cell = (const float*)d_in[3];
  const int* lens = (const int*)d_in[4];
  const float* wih0 = (const float*)d_in[5];
  const float* whh0 = (const float*)d_in[6];
  const float* bih0 = (const float*)d_in[7];
  const float* bhh0 = (const float*)d_in[8];
  const float* wih1 = (const float*)d_in[9];
  const float* whh1 = (const float*)d_in[10];
  const float* bih1 = (const float*)d_in[11];
  const float* bhh1 = (const float*)d_in[12];
  const float* w1 = (const float*)d_in[13];
  const float* b1 = (const float*)d_in[14];
  const float* w2 = (const float*)d_in[15];
  const float* b2 = (const float*)d_in[16];
  float* out = (float*)d_out;

  char* ws = (char*)d_ws;
  size_t off = 0;
  auto alloc = [&](size_t bytes) -> void* {
    void* p = ws + off;
    off += (bytes + 255) & ~(size_t)255;
    return p;
  };
  unsigned short* wih0_b = (unsigned short*)alloc(2097152ull * 2);
  unsigned short* whh0_b = (unsigned short*)alloc(4194304ull * 2);
  unsigned short* wih1_b = (unsigned short*)alloc(4194304ull * 2);
  unsigned short* whh1_b = (unsigned short*)alloc(4194304ull * 2);
  unsigned short* w1_b = (unsigned short*)alloc(1048576ull * 2);
  unsigned short* w2_b = (unsigned short*)alloc(262144ull * 2);
  float* bias0 = (float*)alloc(4096 * 4);
  float* bias1p = (float*)alloc(4096 * 4);
  float* hstate = (float*)alloc(131072ull * 4);
  float* cstate = (float*)alloc(131072ull * 4);
  unsigned short* h0buf = (unsigned short*)alloc(131072ull * 2);  // 2 parity x 65536
  unsigned short* h1buf = (unsigned short*)alloc(131072ull * 2);
  float* pre1buf = (float*)alloc(524288ull * 4);                  // 2 parity x 1 MB
  unsigned* bar = (unsigned*)alloc(16384);
  float* G2a = (float*)alloc(16777216ull * 4);        // G2 chunk buffer A / MLP hidden
  float* G2b = (float*)alloc(16777216ull * 4);        // G2 chunk buffer B
  unsigned short* h1out = (unsigned short*)alloc(16777216ull * 2);

  cvt_kernel<<<2048, 256, 0, stream>>>(wih0, wih0_b, 2097152);
  cvt_kernel<<<4096, 256, 0, stream>>>(whh0, whh0_b, 4194304);
  cvt_kernel<<<4096, 256, 0, stream>>>(wih1, wih1_b, 4194304);
  cvt_kernel<<<4096, 256, 0, stream>>>(whh1, whh1_b, 4194304);
  cvt_kernel<<<1024, 256, 0, stream>>>(w1, w1_b, 1048576);
  cvt_kernel<<<256, 256, 0, stream>>>(w2, w2_b, 262144);

  prep_kernel<<<128, 256, 0, stream>>>(clstm, hidden, cell, lens, hstate, cstate,
                                       h0buf, h1buf, bih0, bhh0, bih1, bhh1,
                                       bias0, bias1p, bar);

  // chunk-0 G2 (standalone); chunks 1..3 computed inside rec2's spare CUs
  gemm_kernel<1, 0><<<dim3(32, 32), 256, 0, stream>>>(x, wih0_b, G2a, bias0, lens,
                                                      4096, 4096, 512, 0);
  for (int c = 0; c < 4; ++c) {
    float* Gc = (c & 1) ? G2b : G2a;
    float* Gn = (c & 1) ? G2a : G2b;
    rec2_kernel<<<256, 512, 0, stream>>>(whh0_b, wih1_b, whh1_b, Gc, bias1p,
                                         h0buf, h1buf, pre1buf, hstate, cstate,
                                         h1out, lens, c * 64, (c == 3) ? 66 : 64, bar,
                                         x, wih0_b, Gn, bias0, (c + 1) * 64,
                                         (c < 3) ? 1 : 0);
  }
  // MLP head (G2a is free after chunk 2 consumed it)
  gemm_kernel<0, 1><<<dim3(8, 128), 256, 0, stream>>>(h1out, w1_b, (void*)G2a, b1, lens,
                                                      16384, 1024, 1024, 0);
  gemm_kernel<0, 2><<<dim3(2, 128), 256, 0, stream>>>((const void*)G2a, w2_b, out, b2, lens,
                                                      16384, 256, 1024, 0);
  final_kernel<<<512, 256, 0, stream>>>(hstate, cstate, lens, out);
}

// Round 8
// 1831.066 us; speedup vs baseline: 1.6137x; 1.0256x over previous
//
#include <hip/hip_runtime.h>

// ============================================================================
// SelectionRNN on MI355X — round 15: round 14 + MLP1-even embedded in c=3 +
// merged cvt.
// Round 14 post-mortem: WIN 2038->1878us as predicted (rec2 +6.5us/dispatch,
// -185us of standalone GEMM+gaps). Playbook confirmed: fill idle CUs with the
// serialized tail; the rec interval itself is a latency chain (ignored 1TB/s
// of co-traffic).
// This round:
//  * c=3 dispatch's embedded slot (was idle, do_gemm=0) now computes the
//    EVEN-t half of MLP1 (h1out[t<128] @ w1^T, relu, bf16 -> G2a). Those
//    rows complete in chunks 0..2 (t<=189 by end of c=2) => visible at c=3
//    dispatch boundary; disjoint from rec's concurrent t>=190 writes.
//  * post-rec MLP1 runs only the ODD half: grid (8,64), t0=1 -> m0=by*256+128.
//  * six cvt launches merged into one cvt6_kernel (segment switch).
// rec path (bid<192) byte-identical to round 14/11.
// gmode: 0=none, 1=next-chunk G2 (wts=wih0_b,bias=bias0), 2=MLP1-even
// (wts=w1_b,bias=b1, A=h1out, out=Gnext as ushort).
// ============================================================================

typedef __bf16 bf16x8 __attribute__((ext_vector_type(8)));
typedef float f32x4 __attribute__((ext_vector_type(4)));
typedef int i32x4 __attribute__((ext_vector_type(4)));

__device__ __forceinline__ unsigned short f2bf(float f) {
  unsigned u = __float_as_uint(f);
  u = u + 0x7FFFu + ((u >> 16) & 1u);   // RNE (inputs finite)
  return (unsigned short)(u >> 16);
}
__device__ __forceinline__ float sigm_(float x) { return 1.f / (1.f + __expf(-x)); }
__device__ __forceinline__ float tanh_(float x) { return 1.f - 2.f / (__expf(2.f * x) + 1.f); }

// fragment-order element offset for h value of (batch b, unit u):
__device__ __forceinline__ int hxoff(int b, int u) {
  return (b >> 4) * 16384 + (u >> 5) * 512 + ((u >> 3) & 3) * 128 + (b & 15) * 8 + (u & 7);
}

// ---------------------------------------------------------------------------
// merged f32->bf16 weight conversion: 6 segments, 15,990,784 elements total.
// grid 15616 x 256 (exact).
// ---------------------------------------------------------------------------
__global__ void cvt6_kernel(
    const float* __restrict__ wih0, const float* __restrict__ whh0,
    const float* __restrict__ wih1, const float* __restrict__ whh1,
    const float* __restrict__ w1, const float* __restrict__ w2,
    unsigned short* __restrict__ wih0b, unsigned short* __restrict__ whh0b,
    unsigned short* __restrict__ wih1b, unsigned short* __restrict__ whh1b,
    unsigned short* __restrict__ w1b, unsigned short* __restrict__ w2b) {
  size_t i = (size_t)(blockIdx.x * 256 + threadIdx.x) * 4;
  const float* s; unsigned short* d; size_t off;
  if (i < 2097152)       { s = wih0; d = wih0b; off = 0; }
  else if (i < 6291456)  { s = whh0; d = whh0b; off = 2097152; }
  else if (i < 10485760) { s = wih1; d = wih1b; off = 6291456; }
  else if (i < 14680064) { s = whh1; d = whh1b; off = 10485760; }
  else if (i < 15728640) { s = w1;   d = w1b;   off = 14680064; }
  else                   { s = w2;   d = w2b;   off = 15728640; }
  i -= off;
  float4 v = *reinterpret_cast<const float4*>(s + i);
  ushort4 o = make_ushort4(f2bf(v.x), f2bf(v.y), f2bf(v.z), f2bf(v.w));
  *reinterpret_cast<ushort4*>(d + i) = o;
}

// ---------------------------------------------------------------------------
// prep: weighted hidden, state init, hX init (fragment order), bias prep,
// barrier clear. grid 128 (l=blk>>6, b=blk&63) x 256.
// h0 initial -> parity 0; h1 initial -> parity 1 (lag-2 pipeline).
// ---------------------------------------------------------------------------
__global__ __launch_bounds__(256) void prep_kernel(
    const float* __restrict__ clstm, const float* __restrict__ hidden,
    const float* __restrict__ cell, const int* __restrict__ lens,
    float* __restrict__ hstate, float* __restrict__ cstate,
    unsigned short* __restrict__ h0buf, unsigned short* __restrict__ h1buf,
    const float* __restrict__ bih0, const float* __restrict__ bhh0,
    const float* __restrict__ bih1, const float* __restrict__ bhh1,
    float* __restrict__ bias0, float* __restrict__ bias1p,
    unsigned* __restrict__ bar) {
  const int tid = threadIdx.x, blk = blockIdx.x;
  const int l = blk >> 6, b = blk & 63;
  const float* crow = clstm + b * 1024;
  const float* hrow = hidden + ((size_t)l * 64 + b) * 1024;
  float cmn = 3.4e38f, cmx = -3.4e38f, hmn = 3.4e38f, hmx = -3.4e38f;
  for (int i = tid; i < 1024; i += 256) {
    float c = crow[i], h = hrow[i];
    cmn = fminf(cmn, c); cmx = fmaxf(cmx, c);
    hmn = fminf(hmn, h); hmx = fmaxf(hmx, h);
  }
#pragma unroll
  for (int off = 32; off > 0; off >>= 1) {
    cmn = fminf(cmn, __shfl_xor(cmn, off));
    cmx = fmaxf(cmx, __shfl_xor(cmx, off));
    hmn = fminf(hmn, __shfl_xor(hmn, off));
    hmx = fmaxf(hmx, __shfl_xor(hmx, off));
  }
  __shared__ float red[4][4];
  int wv = tid >> 6;
  if ((tid & 63) == 0) { red[wv][0] = cmn; red[wv][1] = cmx; red[wv][2] = hmn; red[wv][3] = hmx; }
  __syncthreads();
  cmn = fminf(fminf(red[0][0], red[1][0]), fminf(red[2][0], red[3][0]));
  cmx = fmaxf(fmaxf(red[0][1], red[1][1]), fmaxf(red[2][1], red[3][1]));
  hmn = fminf(fminf(red[0][2], red[1][2]), fminf(red[2][2], red[3][2]));
  hmx = fmaxf(fmaxf(red[0][3], red[1][3]), fmaxf(red[2][3], red[3][3]));
  const float crange = cmx - cmn, hrange = hmx - hmn;
  const int len = lens[b];
  const size_t base = ((size_t)l * 64 + b) * 1024;
  unsigned short* dst = (l == 0) ? h0buf : (h1buf + 65536);  // h1 -> parity 1
  for (int i = tid; i < 1024; i += 256) {
    float cv = crow[i], hv = hrow[i];
    float s = (crange > 0.f) ? (cv - cmn) / crange : cv;
    float s2 = (hrange > 0.f) ? (hmn + s * hrange) : s;
    float cc = (len == 0) ? cv : s2;
    float w = 0.5f * hv + 0.5f * cc;          // HIDDEN_WEIGHT = 0.5
    hstate[base + i] = w;
    cstate[base + i] = cell[base + i];
    dst[hxoff(b, i)] = f2bf(w);
  }
  if (blk == 0) {
    for (int n = tid; n < 4096; n += 256) {
      bias0[n] = bih0[n] + bhh0[n];
      bias1p[(n & 1023) * 4 + (n >> 10)] = bih1[n] + bhh1[n];
      bar[n] = 0u;
    }
  }
}

// ---------------------------------------------------------------------------
// bf16 MFMA GEMM, 128x128 tile. EPI 0 scatters into rec G2 layout.
// EPI 1 with t0!=0: odd-M-tile mode (m0 = by*256+128) for the MLP1 odd half.
// ---------------------------------------------------------------------------
template <int AMODE, int EPI>
__global__ __launch_bounds__(256) void gemm_kernel(
    const void* __restrict__ Ap, const unsigned short* __restrict__ Bw,
    void* __restrict__ Cout, const float* __restrict__ bias,
    const int* __restrict__ lens, int M, int N, int K, int t0) {
  __shared__ unsigned short Al[128][40];
  __shared__ unsigned short Bl[128][40];
  const int tid = threadIdx.x;
  const int m0 = (AMODE == 0 && EPI == 1 && t0 != 0) ? (blockIdx.y * 256 + 128)
                                                     : blockIdx.y * 128;
  const int n0 = blockIdx.x * 128;
  const int srow = tid >> 2;
  const int c8 = (tid & 3) * 8;
  size_t aoff0, aoff1;
  {
    int r = m0 + srow, r2 = r + 64;
    if (AMODE == 0) {
      aoff0 = (size_t)r * K; aoff1 = (size_t)r2 * K;
    } else {
      aoff0 = ((size_t)(r & 63) * 256 + t0 + (r >> 6)) * K;
      aoff1 = ((size_t)(r2 & 63) * 256 + t0 + (r2 >> 6)) * K;
    }
  }
  const size_t boff0 = (size_t)(n0 + srow) * K, boff1 = (size_t)(n0 + srow + 64) * K;
  const int wave = tid >> 6, lane = tid & 63, ln = lane & 15, quad = lane >> 4;
  const int mq = (wave >> 1) * 64, nq = (wave & 1) * 64;
  f32x4 acc[4][4] = {};
  const int nkt = K >> 5;
  for (int kt = 0; kt < nkt; ++kt) {
    const int kc = kt * 32 + c8;
    if (AMODE == 1) {
      const float* A = (const float*)Ap;
      const float* p0 = A + aoff0 + kc;
      const float* p1 = A + aoff1 + kc;
      float4 v0 = *reinterpret_cast<const float4*>(p0);
      float4 v0b = *reinterpret_cast<const float4*>(p0 + 4);
      float4 v1 = *reinterpret_cast<const float4*>(p1);
      float4 v1b = *reinterpret_cast<const float4*>(p1 + 4);
      *reinterpret_cast<ushort4*>(&Al[srow][c8]) =
          make_ushort4(f2bf(v0.x), f2bf(v0.y), f2bf(v0.z), f2bf(v0.w));
      *reinterpret_cast<ushort4*>(&Al[srow][c8 + 4]) =
          make_ushort4(f2bf(v0b.x), f2bf(v0b.y), f2bf(v0b.z), f2bf(v0b.w));
      *reinterpret_cast<ushort4*>(&Al[srow + 64][c8]) =
          make_ushort4(f2bf(v1.x), f2bf(v1.y), f2bf(v1.z), f2bf(v1.w));
      *reinterpret_cast<ushort4*>(&Al[srow + 64][c8 + 4]) =
          make_ushort4(f2bf(v1b.x), f2bf(v1b.y), f2bf(v1b.z), f2bf(v1b.w));
    } else {
      const unsigned short* A = (const unsigned short*)Ap;
      *reinterpret_cast<int4*>(&Al[srow][c8]) = *reinterpret_cast<const int4*>(A + aoff0 + kc);
      *reinterpret_cast<int4*>(&Al[srow + 64][c8]) = *reinterpret_cast<const int4*>(A + aoff1 + kc);
    }
    *reinterpret_cast<int4*>(&Bl[srow][c8]) = *reinterpret_cast<const int4*>(Bw + boff0 + kc);
    *reinterpret_cast<int4*>(&Bl[srow + 64][c8]) = *reinterpret_cast<const int4*>(Bw + boff1 + kc);
    __syncthreads();
    bf16x8 af[4], bfr[4];
#pragma unroll
    for (int i = 0; i < 4; ++i) {
      af[i] = *reinterpret_cast<const bf16x8*>(&Al[mq + i * 16 + ln][quad * 8]);
      bfr[i] = *reinterpret_cast<const bf16x8*>(&Bl[nq + i * 16 + ln][quad * 8]);
    }
#pragma unroll
    for (int i = 0; i < 4; ++i)
#pragma unroll
      for (int j = 0; j < 4; ++j)
        acc[i][j] = __builtin_amdgcn_mfma_f32_16x16x32_bf16(af[i], bfr[j], acc[i][j], 0, 0, 0);
    __syncthreads();
  }
#pragma unroll
  for (int i = 0; i < 4; ++i) {
    int mmb = m0 + mq + i * 16 + quad * 4;
#pragma unroll
    for (int j = 0; j < 4; ++j) {
      int nn = n0 + nq + j * 16 + ln;
      float bv = bias[nn];
#pragma unroll
      for (int r = 0; r < 4; ++r) {
        int mm = mmb + r;
        float v = acc[i][j][r] + bv;
        if (EPI >= 1) v = fmaxf(v, 0.f);
        if (EPI == 2) {
          if (lens[mm >> 8] == 0) v = 0.f;
          ((float*)Cout)[(size_t)mm * N + nn] = v;
        } else if (EPI == 1) {
          ((unsigned short*)Cout)[(size_t)mm * N + nn] = f2bf(v);
        } else {
          size_t idx = ((size_t)mm * 128 + ((nn >> 3) & 127)) * 32 + (nn & 7) * 4 + (nn >> 10);
          ((float*)Cout)[idx] = v;
        }
      }
    }
  }
}

// ---------------------------------------------------------------------------
// Fused two-layer recurrent kernel + embedded tail work on WGs 192..255.
// Grid MUST be 256 WGs x 512 threads.
// WGs 0..127  (L0): units 8g..8g+7. cols 0..15 = Whh0 gates i,f (bregA);
//   cols 16..31 = Whh0 gates g,o (bregB); cols 32..63 = Wih1 (wlds).
// WGs 128..191(L1): units 16g..16g+15. cols 0..15 = Whh1 gate i (bregA);
//   16..31 = gate f (bregB); 32..63 = gates g,o (wlds).
// WGs 192..255: gmode 1 = chunk-(c+1) G2 GEMM (2 tiles/WG x 8 iters);
//   gmode 2 = MLP1 even-t tiles (h1out[t<128] @ w1^T, relu, bf16 -> Gnext).
// wlds: 32 rows x 1032 shorts. glds[2][64][73] reduce.
// Barrier (rec WGs only): 24 groups x 8 arrive; finisher stores s+1 to 8
// replica flags; threads 0..23 poll (replica bid&7); syncthreads fan-out.
// ---------------------------------------------------------------------------
#define HLo(dst, ptr, off) \
  asm volatile("global_load_dwordx4 %0, %1, off offset:" off " sc0 sc1" \
               : "=v"(dst) : "v"(ptr))
#define HL4(h0, h1, h2, h3, ptr) \
  HLo(h0, ptr, "0"); HLo(h1, ptr, "1024"); HLo(h2, ptr, "2048"); HLo(h3, ptr, "3072")
#define HLF(dst, ptr) \
  asm volatile("global_load_dwordx4 %0, %1, off sc0 sc1" : "=v"(dst) : "v"(ptr))
#define HST(ptr, val) \
  asm volatile("global_store_dwordx4 %0, %1, off sc0 sc1" :: "v"(ptr), "v"(val) : "memory")

__global__ __launch_bounds__(512) void rec2_kernel(
    const unsigned short* __restrict__ whh0b,
    const unsigned short* __restrict__ wih1b,
    const unsigned short* __restrict__ whh1b,
    const float* __restrict__ G2,             // [64*64][128][32] L0 preacts
    const float* __restrict__ bias1p,         // [1024][4]
    unsigned short* __restrict__ h0buf,       // [2][65536] bf16, fragment order
    unsigned short* __restrict__ h1buf,       // [2][65536] bf16, fragment order
    float* __restrict__ pre1buf,              // [2][64][1024][4] f32
    float* __restrict__ hstate, float* __restrict__ cstate,
    unsigned short* __restrict__ h1out,       // [64][256][1024] bf16
    const int* __restrict__ lens, int t0, int nint, unsigned* __restrict__ bar,
    const float* __restrict__ xin,            // [64][256][512] f32 input
    const unsigned short* __restrict__ wemb,  // gmode1: wih0_b; gmode2: w1_b
    float* __restrict__ Gnext,                // gmode1: next G2; gmode2: MLP1 out
    const float* __restrict__ bemb,           // gmode1: bias0; gmode2: b1
    int t0n, int gmode) {
  __shared__ unsigned short wlds[32 * 1032];  // B cols 32..63
  __shared__ float glds[2][64][73];
  __shared__ unsigned short hsh[64][16];
  __shared__ unsigned short Ag[2][128][40];   // embedded gemm A tiles
  __shared__ unsigned short Bg[2][128][40];   // embedded gemm B tiles
  const int tid = threadIdx.x;
  const int bid = blockIdx.x;

  if (bid >= 192) {     // ---- embedded tail work ----
    if (gmode == 0) return;
    const int w = bid - 192;                  // 0..63
    const int half = tid >> 8;                // two 256-thread sub-WGs
    const int tl = tid & 255;
    const int srow = tl >> 2;
    const int c8 = (tl & 3) * 8;
    const int wv = tl >> 6, lane2 = tl & 63, ln2 = lane2 & 15, qd = lane2 >> 4;
    const int mq = (wv >> 1) * 64, nq = (wv & 1) * 64;
    if (gmode == 1) {   // ---- next-chunk G2 GEMM (2 tiles/WG x 8 iters) ----
      for (int it = 0; it < 8; ++it) {
        const int tau = it * 128 + w * 2 + half;        // 0..1023 tile id
        const int m0 = (tau >> 5) * 128, n0 = (tau & 31) * 128;
        size_t aoff0, aoff1;
        {
          int r = m0 + srow, r2 = r + 64;
          aoff0 = ((size_t)(r & 63) * 256 + t0n + (r >> 6)) * 512;
          aoff1 = ((size_t)(r2 & 63) * 256 + t0n + (r2 >> 6)) * 512;
        }
        const size_t boff0 = (size_t)(n0 + srow) * 512;
        const size_t boff1 = (size_t)(n0 + srow + 64) * 512;
        f32x4 acc[4][4] = {};
#pragma unroll 1
        for (int kt = 0; kt < 16; ++kt) {
          const int kc = kt * 32 + c8;
          const float* p0 = xin + aoff0 + kc;
          const float* p1 = xin + aoff1 + kc;
          float4 v0 = *reinterpret_cast<const float4*>(p0);
          float4 v0b = *reinterpret_cast<const float4*>(p0 + 4);
          float4 v1 = *reinterpret_cast<const float4*>(p1);
          float4 v1b = *reinterpret_cast<const float4*>(p1 + 4);
          *reinterpret_cast<ushort4*>(&Ag[half][srow][c8]) =
              make_ushort4(f2bf(v0.x), f2bf(v0.y), f2bf(v0.z), f2bf(v0.w));
          *reinterpret_cast<ushort4*>(&Ag[half][srow][c8 + 4]) =
              make_ushort4(f2bf(v0b.x), f2bf(v0b.y), f2bf(v0b.z), f2bf(v0b.w));
          *reinterpret_cast<ushort4*>(&Ag[half][srow + 64][c8]) =
              make_ushort4(f2bf(v1.x), f2bf(v1.y), f2bf(v1.z), f2bf(v1.w));
          *reinterpret_cast<ushort4*>(&Ag[half][srow + 64][c8 + 4]) =
              make_ushort4(f2bf(v1b.x), f2bf(v1b.y), f2bf(v1b.z), f2bf(v1b.w));
          *reinterpret_cast<int4*>(&Bg[half][srow][c8]) =
              *reinterpret_cast<const int4*>(wemb + boff0 + kc);
          *reinterpret_cast<int4*>(&Bg[half][srow + 64][c8]) =
              *reinterpret_cast<const int4*>(wemb + boff1 + kc);
          __syncthreads();
          bf16x8 af[4], bfr[4];
#pragma unroll
          for (int i = 0; i < 4; ++i) {
            af[i] = *reinterpret_cast<const bf16x8*>(&Ag[half][mq + i * 16 + ln2][qd * 8]);
            bfr[i] = *reinterpret_cast<const bf16x8*>(&Bg[half][nq + i * 16 + ln2][qd * 8]);
          }
#pragma unroll
          for (int i = 0; i < 4; ++i)
#pragma unroll
            for (int j = 0; j < 4; ++j)
              acc[i][j] = __builtin_amdgcn_mfma_f32_16x16x32_bf16(af[i], bfr[j], acc[i][j], 0, 0, 0);
          __syncthreads();
        }
#pragma unroll
        for (int i = 0; i < 4; ++i) {
          int mmb = m0 + mq + i * 16 + qd * 4;
#pragma unroll
          for (int j = 0; j < 4; ++j) {
            int nn = n0 + nq + j * 16 + ln2;
            float bv = bemb[nn];
#pragma unroll
            for (int r = 0; r < 4; ++r) {
              int mm = mmb + r;
              float v = acc[i][j][r] + bv;
              size_t idx = ((size_t)mm * 128 + ((nn >> 3) & 127)) * 32 + (nn & 7) * 4 + (nn >> 10);
              Gnext[idx] = v;
            }
          }
        }
      }
    } else {            // ---- gmode 2: MLP1 even-t tiles (4 iters/half) ----
      for (int it = 0; it < 4; ++it) {
        const int tau = it * 128 + w * 2 + half;        // 0..511
        const int m0 = (tau >> 3) * 256;                // b = tau>>3, t<128
        const int n0 = (tau & 7) * 128;
        const size_t aoff0 = (size_t)(m0 + srow) * 1024;
        const size_t aoff1 = (size_t)(m0 + srow + 64) * 1024;
        const size_t boff0 = (size_t)(n0 + srow) * 1024;
        const size_t boff1 = (size_t)(n0 + srow + 64) * 1024;
        f32x4 acc[4][4] = {};
#pragma unroll 1
        for (int kt = 0; kt < 32; ++kt) {
          const int kc = kt * 32 + c8;
          *reinterpret_cast<int4*>(&Ag[half][srow][c8]) =
              *reinterpret_cast<const int4*>(h1out + aoff0 + kc);
          *reinterpret_cast<int4*>(&Ag[half][srow + 64][c8]) =
              *reinterpret_cast<const int4*>(h1out + aoff1 + kc);
          *reinterpret_cast<int4*>(&Bg[half][srow][c8]) =
              *reinterpret_cast<const int4*>(wemb + boff0 + kc);
          *reinterpret_cast<int4*>(&Bg[half][srow + 64][c8]) =
              *reinterpret_cast<const int4*>(wemb + boff1 + kc);
          __syncthreads();
          bf16x8 af[4], bfr[4];
#pragma unroll
          for (int i = 0; i < 4; ++i) {
            af[i] = *reinterpret_cast<const bf16x8*>(&Ag[half][mq + i * 16 + ln2][qd * 8]);
            bfr[i] = *reinterpret_cast<const bf16x8*>(&Bg[half][nq + i * 16 + ln2][qd * 8]);
          }
#pragma unroll
          for (int i = 0; i < 4; ++i)
#pragma unroll
            for (int j = 0; j < 4; ++j)
              acc[i][j] = __builtin_amdgcn_mfma_f32_16x16x32_bf16(af[i], bfr[j], acc[i][j], 0, 0, 0);
          __syncthreads();
        }
#pragma unroll
        for (int i = 0; i < 4; ++i) {
          int mmb = m0 + mq + i * 16 + qd * 4;
#pragma unroll
          for (int j = 0; j < 4; ++j) {
            int nn = n0 + nq + j * 16 + ln2;
            float bv = bemb[nn];
#pragma unroll
            for (int r = 0; r < 4; ++r) {
              int mm = mmb + r;
              float v = fmaxf(acc[i][j][r] + bv, 0.f);
              ((unsigned short*)Gnext)[(size_t)mm * 1024 + nn] = f2bf(v);
            }
          }
        }
      }
    }
    return;
  }

  // ======================= rec path (round 11 verbatim) =====================
  const bool isL1 = bid >= 128;
  const int g = bid & 127;                    // L0: 0..127; L1: 0..63
  // ---- stage LDS weight cols 32..63 (32 rows; 16 thr/row, 64 shorts ea) ----
  {
    int r = tid >> 4;                         // 0..31
    int c0 = (tid & 15) * 64;
    const unsigned short* src;
    if (!isL1)                                // cols 32..63: Wih1 gates 0..3
      src = wih1b + (size_t)((r >> 3) * 1024 + g * 8 + (r & 7)) * 1024;
    else                                      // cols 32..63: Whh1 gates g,o
      src = whh1b + (size_t)((2 + (r >> 4)) * 1024 + g * 16 + (r & 15)) * 1024;
    const i32x4* s4 = reinterpret_cast<const i32x4*>(src + c0);
    i32x4* dst = reinterpret_cast<i32x4*>(wlds + r * 1032 + c0);
#pragma unroll
    for (int j = 0; j < 8; ++j) dst[j] = s4[j];
  }
  const int wave = tid >> 6, lane = tid & 63, ln = lane & 15, quad = lane >> 4;
  const int mt = wave & 3, kw = wave >> 2;
  // ---- B cols 0..15 (bregA) and 16..31 (bregB) in registers ----
  bf16x8 bregA[16], bregB[16];
  {
    const unsigned short *bpA, *bpB;
    if (!isL1) {
      bpA = whh0b + (size_t)((ln >> 3) * 1024 + g * 8 + (ln & 7)) * 1024 + kw * 512 + quad * 8;
      bpB = whh0b + (size_t)((2 + (ln >> 3)) * 1024 + g * 8 + (ln & 7)) * 1024 + kw * 512 + quad * 8;
    } else {
      bpA = whh1b + (size_t)(g * 16 + ln) * 1024 + kw * 512 + quad * 8;
      bpB = whh1b + (size_t)(1024 + g * 16 + ln) * 1024 + kw * 512 + quad * 8;
    }
#pragma unroll
    for (int kt = 0; kt < 16; ++kt) {
      bregA[kt] = *reinterpret_cast<const bf16x8*>(bpA + kt * 32);
      bregB[kt] = *reinterpret_cast<const bf16x8*>(bpB + kt * 32);
    }
  }
  // ---- per-thread owner state ----
  const int b = tid >> 3, ul = tid & 7;
  const size_t sb0 = (size_t)(isL1 ? 65536 : 0) + (size_t)b * 1024 +
                     (isL1 ? g * 16 + ul : g * 8 + ul);
  float cm0 = cstate[sb0], hm0 = hstate[sb0];
  float cm1 = 0.f, hm1 = 0.f;
  if (isL1) { cm1 = cstate[sb0 + 8]; hm1 = hstate[sb0 + 8]; }
  int lv0 = lens[b];
  const int len = lv0 < 1 ? 1 : lv0;
  int lvA = lens[mt * 16 + ln];
  const int lenmA = lvA < 1 ? 1 : lvA;        // A-lane batch clamp (pre1 mask)
  f32x4 b1a = {0.f, 0.f, 0.f, 0.f}, b1b = {0.f, 0.f, 0.f, 0.f};
  if (isL1) {
    b1a = *reinterpret_cast<const f32x4*>(bias1p + (g * 16 + ul) * 4);
    b1b = *reinterpret_cast<const f32x4*>(bias1p + (g * 16 + 8 + ul) * 4);
  }
  int lenp = 257;
  if (isL1 && tid < 128) { int lv = lens[tid >> 1]; lenp = lv < 1 ? 1 : lv; }
  const int puboff = (tid >> 4) * 16384 + (g >> 2) * 512 + (g & 3) * 128 + (tid & 15) * 8;
  const int pub1off = ((tid >> 1) >> 4) * 16384 + (g >> 1) * 512 +
                      ((g * 2 + (tid & 1)) & 3) * 128 + ((tid >> 1) & 15) * 8;
  const bf16x8 z8 = {};
  const i32x4 zi = {};
  __syncthreads();

  for (int k = 0; k < nint; ++k) {
    const int s = t0 + k;
    const bool actG = (!isL1) && (k < 64);            // L0 gates for step s
    const bool actP = (!isL1) && (s >= 1) && (s <= 256); // L0 pre1(s-1)
    const bool actL = isL1 && (s >= 2);               // L1 step s-2
    if (actG || actP || actL) {
      // ---- pre1 loads first (L1), then h fragment loads ----
      f32x4 pga = {0.f, 0.f, 0.f, 0.f}, pgb = {0.f, 0.f, 0.f, 0.f};
      if (isL1) {
        const float* pr = pre1buf + (size_t)(s & 1) * 262144 +
                          ((size_t)b * 1024 + g * 16) * 4;
        HLF(pga, pr + ul * 4);
        HLF(pgb, pr + (8 + ul) * 4);
      }
      bf16x8 hf[16];
      const unsigned short* p = (isL1 ? h1buf + ((s - 1) & 1) * 65536
                                      : h0buf + (s & 1) * 65536) +
                                mt * 16384 + kw * 8192 + lane * 8;
      HL4(hf[0], hf[1], hf[2], hf[3], p);
      HL4(hf[4], hf[5], hf[6], hf[7], p + 2048);
      HL4(hf[8], hf[9], hf[10], hf[11], p + 4096);
      HL4(hf[12], hf[13], hf[14], hf[15], p + 6144);
      if (actG)
        pga = *reinterpret_cast<const f32x4*>(
            G2 + (((size_t)(k * 64 + b)) * 128 + g) * 32 + ul * 4);
      // ---- MFMA: kt 0..7 overlap tail of h-load ----
      const bool maskA = (!isL1) && ((s - 1) >= lenmA);  // zero h0 for padded
      f32x4 acc0 = {0.f, 0.f, 0.f, 0.f}, acc1 = acc0, acc2 = acc0, acc3 = acc0;
      const unsigned short* wp = wlds + ln * 1032 + kw * 512 + quad * 8;
      asm volatile("s_waitcnt vmcnt(8)" ::: "memory");
      __builtin_amdgcn_sched_barrier(0);
#pragma unroll
      for (int kt = 0; kt < 8; ++kt) {
        const unsigned short* c = wp + kt * 32;
        bf16x8 bC = *reinterpret_cast<const bf16x8*>(c);           // cols 32..47
        bf16x8 bD = *reinterpret_cast<const bf16x8*>(c + 16512);   // cols 48..63
        bf16x8 a_ = hf[kt];
        acc0 = __builtin_amdgcn_mfma_f32_16x16x32_bf16(a_, bregA[kt], acc0, 0, 0, 0);
        acc1 = __builtin_amdgcn_mfma_f32_16x16x32_bf16(a_, bregB[kt], acc1, 0, 0, 0);
        bf16x8 am = maskA ? z8 : a_;   // L0: mask Wih1 input on padded batches
        acc2 = __builtin_amdgcn_mfma_f32_16x16x32_bf16(am, bC, acc2, 0, 0, 0);
        acc3 = __builtin_amdgcn_mfma_f32_16x16x32_bf16(am, bD, acc3, 0, 0, 0);
      }
      asm volatile("s_waitcnt vmcnt(0)" ::: "memory");
      __builtin_amdgcn_sched_barrier(0);
#pragma unroll
      for (int kt = 8; kt < 16; ++kt) {
        const unsigned short* c = wp + kt * 32;
        bf16x8 bC = *reinterpret_cast<const bf16x8*>(c);
        bf16x8 bD = *reinterpret_cast<const bf16x8*>(c + 16512);
        bf16x8 a_ = hf[kt];
        acc0 = __builtin_amdgcn_mfma_f32_16x16x32_bf16(a_, bregA[kt], acc0, 0, 0, 0);
        acc1 = __builtin_amdgcn_mfma_f32_16x16x32_bf16(a_, bregB[kt], acc1, 0, 0, 0);
        bf16x8 am = maskA ? z8 : a_;
        acc2 = __builtin_amdgcn_mfma_f32_16x16x32_bf16(am, bC, acc2, 0, 0, 0);
        acc3 = __builtin_amdgcn_mfma_f32_16x16x32_bf16(am, bD, acc3, 0, 0, 0);
      }
      // ---- kw reduce through LDS (single pass, 64 cols) ----
#pragma unroll
      for (int r = 0; r < 4; ++r) {
        float* gp = &glds[kw][mt * 16 + quad * 4 + r][0];
        gp[ln] = acc0[r]; gp[16 + ln] = acc1[r];
        gp[32 + ln] = acc2[r]; gp[48 + ln] = acc3[r];
      }
      __syncthreads();   // A
      const float* g0 = &glds[0][b][0];
      const float* g1 = &glds[1][b][0];
      if (actG) {        // L0 gates (cols: gate*8+ul)
        float pi = g0[ul] + g1[ul] + pga.x;
        float pf = g0[8 + ul] + g1[8 + ul] + pga.y;
        float pgg = g0[16 + ul] + g1[16 + ul] + pga.z;
        float po = g0[24 + ul] + g1[24 + ul] + pga.w;
        float ig = sigm_(pi), fg = sigm_(pf), gv = tanh_(pgg), og = sigm_(po);
        float cn_ = fg * cm0 + ig * gv;
        float hn_ = og * tanh_(cn_);
        if (s < len) { cm0 = cn_; hm0 = hn_; }
        hsh[b][ul] = f2bf(hm0);
      }
      if (actP) {        // L0 pre1(s-1) = Wih1 @ h0_masked(s-1), f32 float4
        f32x4 pv;
        pv.x = g0[32 + ul] + g1[32 + ul];
        pv.y = g0[40 + ul] + g1[40 + ul];
        pv.z = g0[48 + ul] + g1[48 + ul];
        pv.w = g0[56 + ul] + g1[56 + ul];
        float* pd = pre1buf + (size_t)((s - 1) & 1) * 262144 +
                    (size_t)b * 4096 + g * 32 + ul * 4;
        HST(pd, pv);     // drained after publish, before barrier
      }
      if (actL) {        // L1 gates, 2 units/thread (cols: gate*16+iu)
        {
          float pi = g0[ul] + g1[ul] + pga.x + b1a.x;
          float pf = g0[16 + ul] + g1[16 + ul] + pga.y + b1a.y;
          float pgg = g0[32 + ul] + g1[32 + ul] + pga.z + b1a.z;
          float po = g0[48 + ul] + g1[48 + ul] + pga.w + b1a.w;
          float ig = sigm_(pi), fg = sigm_(pf), gv = tanh_(pgg), og = sigm_(po);
          float cn_ = fg * cm0 + ig * gv;
          float hn_ = og * tanh_(cn_);
          if (s - 2 < len) { cm0 = cn_; hm0 = hn_; }
          hsh[b][ul] = f2bf(hm0);
        }
        {
          int iu = 8 + ul;
          float pi = g0[iu] + g1[iu] + pgb.x + b1b.x;
          float pf = g0[16 + iu] + g1[16 + iu] + pgb.y + b1b.y;
          float pgg = g0[32 + iu] + g1[32 + iu] + pgb.z + b1b.z;
          float po = g0[48 + iu] + g1[48 + iu] + pgb.w + b1b.w;
          float ig = sigm_(pi), fg = sigm_(pf), gv = tanh_(pgg), og = sigm_(po);
          float cn_ = fg * cm1 + ig * gv;
          float hn_ = og * tanh_(cn_);
          if (s - 2 < len) { cm1 = cn_; hm1 = hn_; }
          hsh[b][iu] = f2bf(hm1);
        }
      }
      __syncthreads();   // B
      // ---- publish h (fragment order, 16 B/thread) + drains ----
      if (!isL1) {
        if (actG && tid < 64) {
          i32x4 v = *reinterpret_cast<const i32x4*>(&hsh[tid][0]);
          unsigned short* d = h0buf + ((s + 1) & 1) * 65536 + puboff;
          HST(d, v);
        }
        // drains this thread's pre1 store (all 512 thr) and publish (tid<64)
        asm volatile("s_waitcnt vmcnt(0)" ::: "memory");
      } else {
        if (tid < 128) {
          const int pb = tid >> 1, half = tid & 1;
          i32x4 v = *reinterpret_cast<const i32x4*>(&hsh[pb][half * 8]);
          unsigned short* d = h1buf + (s & 1) * 65536 + pub1off;
          HST(d, v);
          const int t = s - 2;
          i32x4 vo = (t < lenp) ? v : zi;
          *reinterpret_cast<i32x4*>(h1out + ((size_t)pb * 256 + t) * 1024 +
                                    g * 16 + half * 8) = vo;
          // vmcnt(1): h1buf HST (older) retired; h1out store may linger
          // (h1out is only read after kernel end).
          asm volatile("s_waitcnt vmcnt(1)" ::: "memory");
        }
      }
    }
    // ---- barrier: 24 groups x 8 arrive; finisher stores s+1 to 8 replica
    //      flags; threads 0..23 poll (replica bid&7); syncthreads fan-out ----
    __syncthreads();
    if (tid == 0) {
      unsigned a = __hip_atomic_fetch_add(bar + ((bid >> 3) << 4), 1u,
                                          __ATOMIC_RELAXED, __HIP_MEMORY_SCOPE_AGENT);
      if ((a & 7u) == 7u) {
        const unsigned val = (unsigned)(s + 1);
        const int gi = bid >> 3;
#pragma unroll
        for (int rep = 0; rep < 8; ++rep)
          __hip_atomic_store(bar + 1024 + ((gi * 8 + rep) << 4), val,
                             __ATOMIC_RELAXED, __HIP_MEMORY_SCOPE_AGENT);
      }
    }
    if (tid < 24) {
      const unsigned tgt = (unsigned)(s + 1);
      while (__hip_atomic_load(bar + 1024 + ((tid * 8 + (bid & 7)) << 4),
                               __ATOMIC_RELAXED, __HIP_MEMORY_SCOPE_AGENT) < tgt)
        __builtin_amdgcn_s_sleep(2);
    }
    __syncthreads();
  }
  hstate[sb0] = hm0; cstate[sb0] = cm0;
  if (isL1) { hstate[sb0 + 8] = hm1; cstate[sb0 + 8] = cm1; }
}

// ---------------------------------------------------------------------------
__global__ void final_kernel(const float* __restrict__ hstate, const float* __restrict__ cstate,
                             const int* __restrict__ lens, float* __restrict__ out) {
  int i = blockIdx.x * 256 + threadIdx.x;   // [L][B][H]
  int b = (i >> 10) & 63;
  float z = (lens[b] == 0) ? 0.f : 1.f;
  out[4194304 + i] = z * hstate[i];
  out[4325376 + i] = z * cstate[i];
}

// ---------------------------------------------------------------------------
extern "C" void kernel_launch(void* const* d_in, const int* in_sizes, int n_in,
                              void* d_out, int out_size, void* d_ws, size_t ws_size,
                              hipStream_t stream) {
  const float* x = (const float*)d_in[0];
  const float* clstm = (const float*)d_in[1];
  const float* hidden = (const float*)d_in[2];
  const float* cell = (const float*)d_in[3];
  const int* lens = (const int*)d_in[4];
  const float* wih0 = (const float*)d_in[5];
  const float* whh0 = (const float*)d_in[6];
  const float* bih0 = (const float*)d_in[7];
  const float* bhh0 = (const float*)d_in[8];
  const float* wih1 = (const float*)d_in[9];
  const float* whh1 = (const float*)d_in[10];
  const float* bih1 = (const float*)d_in[11];
  const float* bhh1 = (const float*)d_in[12];
  const float* w1 = (const float*)d_in[13];
  const float* b1 = (const float*)d_in[14];
  const float* w2 = (const float*)d_in[15];
  const float* b2 = (const float*)d_in[16];
  float* out = (float*)d_out;

  char* ws = (char*)d_ws;
  size_t off = 0;
  auto alloc = [&](size_t bytes) -> void* {
    void* p = ws + off;
    off += (bytes + 255) & ~(size_t)255;
    return p;
  };
  unsigned short* wih0_b = (unsigned short*)alloc(2097152ull * 2);
  unsigned short* whh0_b = (unsigned short*)alloc(4194304ull * 2);
  unsigned short* wih1_b = (unsigned short*)alloc(4194304ull * 2);
  unsigned short* whh1_b = (unsigned short*)alloc(4194304ull * 2);
  unsigned short* w1_b = (unsigned short*)alloc(1048576ull * 2);
  unsigned short* w2_b = (unsigned short*)alloc(262144ull * 2);
  float* bias0 = (float*)alloc(4096 * 4);
  float* bias1p = (float*)alloc(4096 * 4);
  float* hstate = (float*)alloc(131072ull * 4);
  float* cstate = (float*)alloc(131072ull * 4);
  unsigned short* h0buf = (unsigned short*)alloc(131072ull * 2);  // 2 parity x 65536
  unsigned short* h1buf = (unsigned short*)alloc(131072ull * 2);
  float* pre1buf = (float*)alloc(524288ull * 4);                  // 2 parity x 1 MB
  unsigned* bar = (unsigned*)alloc(16384);
  float* G2a = (float*)alloc(16777216ull * 4);        // G2 chunk buffer A / MLP hidden
  float* G2b = (float*)alloc(16777216ull * 4);        // G2 chunk buffer B
  unsigned short* h1out = (unsigned short*)alloc(16777216ull * 2);

  cvt6_kernel<<<15616, 256, 0, stream>>>(wih0, whh0, wih1, whh1, w1, w2,
                                         wih0_b, whh0_b, wih1_b, whh1_b, w1_b, w2_b);

  prep_kernel<<<128, 256, 0, stream>>>(clstm, hidden, cell, lens, hstate, cstate,
                                       h0buf, h1buf, bih0, bhh0, bih1, bhh1,
                                       bias0, bias1p, bar);

  // chunk-0 G2 (standalone); chunks 1..3 + MLP1-even computed inside rec2
  gemm_kernel<1, 0><<<dim3(32, 32), 256, 0, stream>>>(x, wih0_b, G2a, bias0, lens,
                                                      4096, 4096, 512, 0);
  for (int c = 0; c < 4; ++c) {
    float* Gc = (c & 1) ? G2b : G2a;
    float* Gn = (c & 1) ? G2a : G2b;
    if (c < 3) {
      rec2_kernel<<<256, 512, 0, stream>>>(whh0_b, wih1_b, whh1_b, Gc, bias1p,
                                           h0buf, h1buf, pre1buf, hstate, cstate,
                                           h1out, lens, c * 64, 64, bar,
                                           x, wih0_b, Gn, bias0, (c + 1) * 64, 1);
    } else {
      // c=3: Gc=G2b; embedded WGs compute MLP1 even-t tiles into G2a
      rec2_kernel<<<256, 512, 0, stream>>>(whh0_b, wih1_b, whh1_b, Gc, bias1p,
                                           h0buf, h1buf, pre1buf, hstate, cstate,
                                           h1out, lens, c * 64, 66, bar,
                                           x, w1_b, G2a, b1, 0, 2);
    }
  }
  // MLP head: odd-t half of layer 1, then full layer 2
  gemm_kernel<0, 1><<<dim3(8, 64), 256, 0, stream>>>(h1out, w1_b, (void*)G2a, b1, lens,
                                                     16384, 1024, 1024, 1);
  gemm_kernel<0, 2><<<dim3(2, 128), 256, 0, stream>>>((const void*)G2a, w2_b, out, b2, lens,
                                                      16384, 256, 1024, 0);
  final_kernel<<<512, 256, 0, stream>>>(hstate, cstate, lens, out);
}